// Round 7
// baseline (186.140 us; speedup 1.0000x reference)
//
#include <hip/hip_runtime.h>
#include <hip/hip_bf16.h>

#define S_LEN 2048
#define D_MODEL 2048
#define NH 16
#define NKVH 4
#define HD 128
#define KVB 64
#define EPS_STRIDE 132   // epilogue LDS row stride (f32), 4-aligned, non-pow2

typedef __attribute__((ext_vector_type(8))) short bh8;   // 8 bf16
typedef __attribute__((ext_vector_type(4))) short bh4;   // 4 bf16
typedef __attribute__((ext_vector_type(4))) float f4;
typedef unsigned short u16;
typedef unsigned int u32;

#define GAS __attribute__((address_space(1)))
#define LAS __attribute__((address_space(3)))

__device__ __forceinline__ u16 bf16u(float x) {
    __hip_bfloat16 h = __float2bfloat16(x);
    return __builtin_bit_cast(u16, h);
}
__device__ __forceinline__ float b2f(u16 u) {
    return __builtin_bit_cast(float, (u32)u << 16);
}
__device__ __forceinline__ u32 pack2(float a, float b) {
    return (u32)bf16u(a) | ((u32)bf16u(b) << 16);
}

// ---------------- fp32 -> bf16 elementwise ----------------
__global__ __launch_bounds__(256) void cvt_bf16(const float* __restrict__ in,
                                                u16* __restrict__ out, int n) {
    int i = (blockIdx.x * 256 + threadIdx.x) * 4;
    if (i < n) {
        float4 v = *reinterpret_cast<const float4*>(in + i);
        ushort4 o;
        o.x = bf16u(v.x); o.y = bf16u(v.y); o.z = bf16u(v.z); o.w = bf16u(v.w);
        *reinterpret_cast<ushort4*>(out + i) = o;
    }
}

// ---------------- V transpose: VT[h][d][t] = V[h][t][d], bf16 ----------------
__global__ __launch_bounds__(256) void transpose_v(const float* __restrict__ V,
                                                   u16* __restrict__ VT) {
    __shared__ float tile[32][33];
    int h = blockIdx.z;
    int t0 = blockIdx.x * 32, d0 = blockIdx.y * 32;
    int tx = threadIdx.x & 31, ty = threadIdx.x >> 5;
#pragma unroll
    for (int r = 0; r < 4; ++r) {
        int t = ty + r * 8;
        tile[t][tx] = V[(size_t)h * S_LEN * HD + (size_t)(t0 + t) * HD + d0 + tx];
    }
    __syncthreads();
#pragma unroll
    for (int r = 0; r < 4; ++r) {
        int d = ty + r * 8;
        VT[(size_t)h * HD * S_LEN + (size_t)(d0 + d) * S_LEN + t0 + tx] = bf16u(tile[tx][d]);
    }
}

// ---------------- bf16 NT GEMM, 2-phase dbuf + XCD supertile swizzle --------
template<typename OT>
__global__ __launch_bounds__(256) void gemm_nt(const u16* __restrict__ A,
                                               const u16* __restrict__ B,
                                               OT* __restrict__ C,
                                               int M, int N, int K) {
    __shared__ u16 As[2][128 * 32];
    __shared__ u16 Bs[2][128 * 32];
    const int tid = threadIdx.x;
    const int wid = tid >> 6, lane = tid & 63;

    // XCD supertile swizzle: each XCD gets a compact rectangle of tiles.
    const int gx = gridDim.x, gy = gridDim.y;
    int tx = blockIdx.x, ty = blockIdx.y;
    {
        int total = gx * gy;
        if ((total & 63) == 0 && gx >= 8) {
            int chunk = total >> 3;
            int srows = chunk >> 3;
            if (srows > 0 && (gy % srows) == 0) {
                int bid = blockIdx.y * gx + blockIdx.x;
                int xcd = bid & 7, loc = bid >> 3;
                int nsx = gx >> 3;
                int sqx = xcd % nsx, sqy = xcd / nsx;
                tx = sqx * 8 + (loc & 7);
                ty = sqy * srows + (loc >> 3);
            }
        }
    }
    const int row0 = ty * 128, col0 = tx * 128;
    const int wr = (wid >> 1) * 64, wc = (wid & 1) * 64;

    const int strow = wid * 16 + (lane >> 2);
    const int schunk = (lane & 3) * 8;

    f4 acc[4][4] = {};
    const int fr = lane & 15, fk = (lane >> 4) * 8;

#define GSTAGE(b, k0)                                                             \
    {                                                                             \
        __builtin_amdgcn_global_load_lds(                                         \
            (const GAS void*)(A + (size_t)(row0 + strow) * K + (k0) + schunk),    \
            (LAS void*)(As[b] + wid * 512), 16, 0, 0);                            \
        __builtin_amdgcn_global_load_lds(                                         \
            (const GAS void*)(A + (size_t)(row0 + 64 + strow) * K + (k0) + schunk),\
            (LAS void*)(As[b] + 2048 + wid * 512), 16, 0, 0);                     \
        __builtin_amdgcn_global_load_lds(                                         \
            (const GAS void*)(B + (size_t)(col0 + strow) * K + (k0) + schunk),    \
            (LAS void*)(Bs[b] + wid * 512), 16, 0, 0);                            \
        __builtin_amdgcn_global_load_lds(                                         \
            (const GAS void*)(B + (size_t)(col0 + 64 + strow) * K + (k0) + schunk),\
            (LAS void*)(Bs[b] + 2048 + wid * 512), 16, 0, 0);                     \
    }

    GSTAGE(0, 0);
    __syncthreads();

    const int nk = K >> 5;
    for (int t = 0; t < nk; ++t) {
        const int cur = t & 1;
        if (t + 1 < nk) GSTAGE(cur ^ 1, (t + 1) * 32);

        bh8 af[4], bfv[4];
#pragma unroll
        for (int i = 0; i < 4; ++i) {
            af[i]  = *reinterpret_cast<const bh8*>(&As[cur][(wr + i * 16 + fr) * 32 + fk]);
            bfv[i] = *reinterpret_cast<const bh8*>(&Bs[cur][(wc + i * 16 + fr) * 32 + fk]);
        }
#pragma unroll
        for (int i = 0; i < 4; ++i)
#pragma unroll
            for (int j = 0; j < 4; ++j)
                acc[i][j] = __builtin_amdgcn_mfma_f32_16x16x32_bf16(af[i], bfv[j], acc[i][j], 0, 0, 0);
        __syncthreads();
    }
#undef GSTAGE

    const int orow = (lane >> 4) * 4, ocol = lane & 15;
#pragma unroll
    for (int i = 0; i < 4; ++i)
#pragma unroll
        for (int j = 0; j < 4; ++j)
#pragma unroll
            for (int e = 0; e < 4; ++e) {
                float v = acc[i][j][e];
                size_t off = (size_t)(row0 + wr + i * 16 + orow + e) * N + col0 + wc + j * 16 + ocol;
                if constexpr (__is_same(OT, u16)) C[off] = bf16u(v);
                else C[off] = v;
            }
}

// ---------------- q prep: RMS + partial RoPE + fold SCALE*log2e, bf16 --------
__global__ __launch_bounds__(256) void qprep(const u16* __restrict__ C1b,
                                             const float* __restrict__ cosb,
                                             const float* __restrict__ sinb,
                                             const float* __restrict__ qw,
                                             u16* __restrict__ Qb) {
    constexpr float KS = 0.08838834764831845f * 1.4426950408889634f;
    int wid = threadIdx.x >> 6, lane = threadIdx.x & 63;
    int id = blockIdx.x * 4 + wid;          // (h,s) index
    int h = id >> 11, s = id & 2047;
    const u16* row = C1b + (size_t)s * 4096 + h * 256;
    float v0 = b2f(row[lane]), v1 = b2f(row[lane + 64]);
    float ss = v0 * v0 + v1 * v1;
#pragma unroll
    for (int off = 32; off; off >>= 1) ss += __shfl_xor(ss, off, 64);
    float sc = rsqrtf(ss * (1.f / 128.f) + 1e-6f);
    float q0 = v0 * sc * (1.f + qw[lane]);
    float q1 = v1 * sc * (1.f + qw[lane + 64]);
    float part = __shfl_xor(q0, 32, 64);
    float rot = (lane < 32) ? -part : part;
    float c = cosb[s * 64 + lane], sn = sinb[s * 64 + lane];
    float o0 = q0 * c + rot * sn;
    u16* dst = Qb + (size_t)h * S_LEN * HD + (size_t)s * HD;
    dst[lane] = bf16u(o0 * KS);
    dst[lane + 64] = bf16u(q1 * KS);
}

// ---------------- flash attention, swapped-QK, KV-split ----------------------
// S^T = mfma(K,Q): each lane owns one q-row -> softmax is in-lane + 2 shuffles,
// P stays in registers and feeds PV's B-operand directly (k-slot permutation
// absorbed into sigma-permuted V^T reads). O^T transposed via LDS in epilogue.
__global__ __launch_bounds__(256, 4) void attn_kernel(const u16* __restrict__ Qb,
                                                      const u16* __restrict__ Kb,
                                                      const u16* __restrict__ VTb,
                                                      u16* __restrict__ O0p,
                                                      u16* __restrict__ O1p,
                                                      float* __restrict__ M0,
                                                      float* __restrict__ L0,
                                                      float* __restrict__ M1,
                                                      float* __restrict__ L1) {
    __shared__ __align__(16) char buf[4 * 16 * EPS_STRIDE * 4];  // 33792 B
    u16* Kt = (u16*)buf;                 // 16 KiB  [64 kv][128 d], swizzled chunks
    u16* Vt = (u16*)(buf + 16384);       // 16 KiB  [128 d][64 kv], swizzled chunks

    const int tid = threadIdx.x, wid = tid >> 6, lane = tid & 63;
    const int bid = blockIdx.x;          // 0..1023
    const int half = bid & 1;
    const int rest = bid >> 1;
    const int h = rest & 15;
    const int qb = 31 - (rest >> 4);     // LPT
    const int q0w = qb * 64 + wid * 16;
    const int h4 = h >> 2;
    const u16* Qh = Qb + (size_t)h * S_LEN * HD;
    const u16* Kh = Kb + (size_t)h4 * S_LEN * HD;
    const u16* Vh = VTb + (size_t)h4 * HD * S_LEN;
    const int fr = lane & 15, hi4 = lane >> 4;
    const int sx = fr & 7;
    constexpr float THR = 11.5f;

    const int nt0 = (qb + 1) >> 1;
    const int tb = half ? nt0 : 0;
    const int te = half ? (qb + 1) : nt0;
    const int qrow = q0w + fr;           // this lane's q-row

    bh8 qf[4];
#pragma unroll
    for (int kb = 0; kb < 4; ++kb)
        qf[kb] = *reinterpret_cast<const bh8*>(&Qh[(size_t)qrow * HD + kb * 32 + hi4 * 8]);

    f4 acc[8] = {};                      // O^T: acc[dt][j] -> d=dt*16+hi4*4+j, q=qrow
    float m_r = -1e30f, l_r = 0.f;

    bh8 kreg[4], vreg[4];
    auto load_next = [&](int t0) {
#pragma unroll
        for (int i = 0; i < 4; ++i) {
            int row = wid * 16 + i * 4 + (lane >> 4);
            int ck = (lane & 15) ^ (row & 7);
            kreg[i] = *reinterpret_cast<const bh8*>(Kh + (size_t)(t0 + row) * HD + ck * 8);
        }
#pragma unroll
        for (int i = 0; i < 4; ++i) {
            int row = wid * 32 + i * 8 + (lane >> 3);
            int cv = (lane & 7) ^ (row & 7);
            vreg[i] = *reinterpret_cast<const bh8*>(Vh + (size_t)row * S_LEN + t0 + cv * 8);
        }
    };
    auto store_next = [&]() {
#pragma unroll
        for (int i = 0; i < 4; ++i)
            *reinterpret_cast<bh8*>(&Kt[(wid * 16 + i * 4) * HD + lane * 8]) = kreg[i];
#pragma unroll
        for (int i = 0; i < 4; ++i)
            *reinterpret_cast<bh8*>(&Vt[(wid * 32 + i * 8) * KVB + lane * 8]) = vreg[i];
    };

    auto tile_step = [&](int t0, bool masked) {
        // QK^T swapped: z[nf][j] = S^T[kv = t0+nf*16+hi4*4+j][q = qrow] (log2 units)
        f4 z[4];
#pragma unroll
        for (int nf = 0; nf < 4; ++nf) {
            f4 zz = {};
#pragma unroll
            for (int kb = 0; kb < 4; ++kb) {
                bh8 kf = *reinterpret_cast<const bh8*>(
                    &Kt[(nf * 16 + fr) * HD + (((kb * 4 + hi4) ^ sx) * 8)]);
                zz = __builtin_amdgcn_mfma_f32_16x16x32_bf16(kf, qf[kb], zz, 0, 0, 0);
            }
            z[nf] = zz;
        }
        if (masked) {
#pragma unroll
            for (int nf = 0; nf < 4; ++nf)
#pragma unroll
                for (int j = 0; j < 4; ++j)
                    if (t0 + nf * 16 + hi4 * 4 + j > qrow) z[nf][j] = -3.0e38f;
        }
        // row max: 15 in-lane + 2 shuffles (across hi4 groups)
        float v = z[0][0];
#pragma unroll
        for (int nf = 0; nf < 4; ++nf)
#pragma unroll
            for (int j = 0; j < 4; ++j) v = fmaxf(v, z[nf][j]);
        v = fmaxf(v, __shfl_xor(v, 16, 64));
        v = fmaxf(v, __shfl_xor(v, 32, 64));
        if (__any(v > m_r + THR)) {
            float nm = fmaxf(m_r, v);
            float corr = exp2f(m_r - nm);
            m_r = nm;
            l_r *= corr;
#pragma unroll
            for (int dt = 0; dt < 8; ++dt)
#pragma unroll
                for (int j = 0; j < 4; ++j) acc[dt][j] *= corr;
        }
        // exp + partial l + pack to bf16 (lane keeps its own q-row's P)
        u32 pk[4][2];
#pragma unroll
        for (int nf = 0; nf < 4; ++nf) {
            float p0 = exp2f(z[nf][0] - m_r), p1 = exp2f(z[nf][1] - m_r);
            float p2 = exp2f(z[nf][2] - m_r), p3 = exp2f(z[nf][3] - m_r);
            l_r += (p0 + p1) + (p2 + p3);
            pk[nf][0] = pack2(p0, p1);
            pk[nf][1] = pack2(p2, p3);
        }
        // PV: pa = lane's own 8 p-values per 32-kv block; V^T sigma-permuted reads
#pragma unroll
        for (int kk = 0; kk < 2; ++kk) {
            union { u32 w[4]; bh8 v8; } u;
            u.w[0] = pk[2 * kk][0];     u.w[1] = pk[2 * kk][1];
            u.w[2] = pk[2 * kk + 1][0]; u.w[3] = pk[2 * kk + 1][1];
            bh8 pa = u.v8;
            const int cA = kk * 4 + (hi4 >> 1);
            const int off = (hi4 & 1) * 4;
#pragma unroll
            for (int dt = 0; dt < 8; ++dt) {
                int base = (dt * 16 + fr) * KVB;
                bh4 lo = *reinterpret_cast<const bh4*>(&Vt[base + ((cA ^ sx) * 8) + off]);
                bh4 hi = *reinterpret_cast<const bh4*>(&Vt[base + (((cA + 2) ^ sx) * 8) + off]);
                bh8 vf = __builtin_shufflevector(lo, hi, 0, 1, 2, 3, 4, 5, 6, 7);
                acc[dt] = __builtin_amdgcn_mfma_f32_16x16x32_bf16(vf, pa, acc[dt], 0, 0, 0);
            }
        }
    };

    if (tb < te) {
        load_next(tb * KVB);
        store_next();
        __syncthreads();
        for (int t = tb; t < te - 1; ++t) {
            load_next((t + 1) * KVB);
            tile_step(t * KVB, false);
            __syncthreads();
            store_next();
            __syncthreads();
        }
        tile_step((te - 1) * KVB, (te - 1) == qb);
    }

    // epilogue: reduce l across hi4 groups; transpose O^T via LDS; bf16 partials
    float l_tot = l_r;
    l_tot += __shfl_xor(l_tot, 16, 64);
    l_tot += __shfl_xor(l_tot, 32, 64);

    u16* Op = half ? O1p : O0p;
    float* Mp = half ? M1 : M0;
    float* Lp = half ? L1 : L0;
    if (hi4 == 0) {
        Mp[h * S_LEN + qrow] = m_r;
        Lp[h * S_LEN + qrow] = l_tot;
    }

    __syncthreads();                     // everyone done with Kt/Vt
    float* ep = (float*)buf + wid * (16 * EPS_STRIDE);
#pragma unroll
    for (int dt = 0; dt < 8; ++dt)
#pragma unroll
        for (int j = 0; j < 4; ++j)
            ep[fr * EPS_STRIDE + dt * 16 + hi4 * 4 + j] = acc[dt][j];
    asm volatile("s_waitcnt lgkmcnt(0)" ::: "memory");   // per-wave private region

    const int q_l = lane >> 2;           // 0..15
    const int c0 = (lane & 3) * 32;      // d base
    const float* eprow = ep + q_l * EPS_STRIDE + c0;
    u16* dst = Op + ((size_t)h * S_LEN + (q0w + q_l)) * HD + c0;
#pragma unroll
    for (int i2 = 0; i2 < 4; ++i2) {
        f4 a = *reinterpret_cast<const f4*>(eprow + i2 * 8);
        f4 b = *reinterpret_cast<const f4*>(eprow + i2 * 8 + 4);
        uint4 w;
        w.x = pack2(a[0], a[1]); w.y = pack2(a[2], a[3]);
        w.z = pack2(b[0], b[1]); w.w = pack2(b[2], b[3]);
        *reinterpret_cast<uint4*>(dst + i2 * 8) = w;
    }
}

// ---------------- combine: merge 2 KV-halves, gate, emit bf16 AO -------------
__global__ __launch_bounds__(256) void attn_combine(const u16* __restrict__ O0p,
                                                    const u16* __restrict__ O1p,
                                                    const float* __restrict__ M0,
                                                    const float* __restrict__ L0,
                                                    const float* __restrict__ M1,
                                                    const float* __restrict__ L1,
                                                    const u16* __restrict__ C1b,
                                                    u16* __restrict__ AO) {
    constexpr float L2E = 1.4426950408889634f;
    int idx = blockIdx.x * 256 + threadIdx.x;   // 16*2048*16 total
    int d8 = idx & 15;
    int s  = (idx >> 4) & 2047;
    int h  = idx >> 15;
    int row = h * S_LEN + s;
    float m0 = M0[row], l0 = L0[row], m1 = M1[row], l1 = L1[row];
    float m = fmaxf(m0, m1);
    float a = exp2f(m0 - m), b = exp2f(m1 - m);
    float inv = 1.f / (a * l0 + b * l1);
    bh8 o0 = *reinterpret_cast<const bh8*>(O0p + (size_t)row * HD + d8 * 8);
    bh8 o1 = *reinterpret_cast<const bh8*>(O1p + (size_t)row * HD + d8 * 8);
    bh8 g  = *reinterpret_cast<const bh8*>(C1b + (size_t)s * 4096 + h * 256 + 128 + d8 * 8);
    u32 w[4];
#pragma unroll
    for (int e = 0; e < 4; ++e) {
        float v0 = (a * b2f((u16)o0[2 * e]) + b * b2f((u16)o1[2 * e])) * inv;
        float v1 = (a * b2f((u16)o0[2 * e + 1]) + b * b2f((u16)o1[2 * e + 1])) * inv;
        v0 *= 1.f / (1.f + exp2f(-b2f((u16)g[2 * e]) * L2E));
        v1 *= 1.f / (1.f + exp2f(-b2f((u16)g[2 * e + 1]) * L2E));
        w[e] = pack2(v0, v1);
    }
    uint4 ww = {w[0], w[1], w[2], w[3]};
    *reinterpret_cast<uint4*>(AO + (size_t)s * D_MODEL + h * HD + d8 * 8) = ww;
}

extern "C" void kernel_launch(void* const* d_in, const int* in_sizes, int n_in,
                              void* d_out, int out_size, void* d_ws, size_t ws_size,
                              hipStream_t stream) {
    const float* hs   = (const float*)d_in[0];
    const float* Kc   = (const float*)d_in[1];
    const float* Vc   = (const float*)d_in[2];
    const float* cosb = (const float*)d_in[3];
    const float* sinb = (const float*)d_in[4];
    const float* Wq   = (const float*)d_in[6];
    const float* Wo   = (const float*)d_in[9];
    const float* qw   = (const float*)d_in[10];
    float* out = (float*)d_out;

    char* ws = (char*)d_ws;
    u16*   x_bf  = (u16*)ws;                          // 8 MiB  (dead after gemm1)
    u16*   Wq_bf = (u16*)(ws + (8u << 20));           // 16 MiB (dead after gemm1)
    u16*   Wo_bf = (u16*)(ws + (24u << 20));          // 8 MiB  (live till gemm2)
    u16*   K_bf  = (u16*)(ws + (32u << 20));          // 2 MiB
    u16*   VT_bf = (u16*)(ws + (34u << 20));          // 2 MiB
    u16*   C1b   = (u16*)(ws + (36u << 20));          // 16 MiB bf16 (q|gate)
    u16*   Qb    = (u16*)(ws + (68u << 20));          // 8 MiB
    u16*   AO    = (u16*)(ws + (76u << 20));          // 8 MiB
    // attn partials overlay the dead x_bf/Wq_bf region:
    u16*   O0p   = (u16*)ws;                          // 8 MiB
    u16*   O1p   = (u16*)(ws + (8u << 20));           // 8 MiB
    float* M0    = (float*)(ws + (16u << 20));        // 128 KiB each
    float* L0    = M0 + NH * S_LEN;
    float* M1    = L0 + NH * S_LEN;
    float* L1    = M1 + NH * S_LEN;

    cvt_bf16<<<4096, 256, 0, stream>>>(hs, x_bf, 2048 * 2048);
    cvt_bf16<<<8192, 256, 0, stream>>>(Wq, Wq_bf, 4096 * 2048);
    cvt_bf16<<<4096, 256, 0, stream>>>(Wo, Wo_bf, 2048 * 2048);
    cvt_bf16<<<1024, 256, 0, stream>>>(Kc, K_bf, NKVH * S_LEN * HD);
    transpose_v<<<dim3(64, 4, NKVH), 256, 0, stream>>>(Vc, VT_bf);

    gemm_nt<u16><<<dim3(32, 16), 256, 0, stream>>>(x_bf, Wq_bf, C1b, 2048, 4096, 2048);
    qprep<<<8192, 256, 0, stream>>>(C1b, cosb, sinb, qw, Qb);
    attn_kernel<<<1024, 256, 0, stream>>>(Qb, K_bf, VT_bf, O0p, O1p, M0, L0, M1, L1);
    attn_combine<<<2048, 256, 0, stream>>>(O0p, O1p, M0, L0, M1, L1, C1b, AO);
    gemm_nt<float><<<dim3(16, 16), 256, 0, stream>>>(AO, Wo_bf, out, 2048, 2048, 2048);
}

// Round 8
// 172.372 us; speedup vs baseline: 1.0799x; 1.0799x over previous
//
#include <hip/hip_runtime.h>
#include <hip/hip_bf16.h>

#define S_LEN 2048
#define D_MODEL 2048
#define NH 16
#define NKVH 4
#define HD 128
#define KVB 64
#define EPS_STRIDE 132   // epilogue LDS row stride (f32), 4-aligned, non-pow2

typedef __attribute__((ext_vector_type(8))) short bh8;   // 8 bf16
typedef __attribute__((ext_vector_type(4))) short bh4;   // 4 bf16
typedef __attribute__((ext_vector_type(4))) float f4;
typedef unsigned short u16;
typedef unsigned int u32;

#define GAS __attribute__((address_space(1)))
#define LAS __attribute__((address_space(3)))

__device__ __forceinline__ u16 bf16u(float x) {
    __hip_bfloat16 h = __float2bfloat16(x);
    return __builtin_bit_cast(u16, h);
}
__device__ __forceinline__ float b2f(u16 u) {
    return __builtin_bit_cast(float, (u32)u << 16);
}
__device__ __forceinline__ u32 pack2(float a, float b) {
    return (u32)bf16u(a) | ((u32)bf16u(b) << 16);
}

// ---------------- fp32 -> bf16 elementwise ----------------
__global__ __launch_bounds__(256) void cvt_bf16(const float* __restrict__ in,
                                                u16* __restrict__ out, int n) {
    int i = (blockIdx.x * 256 + threadIdx.x) * 4;
    if (i < n) {
        float4 v = *reinterpret_cast<const float4*>(in + i);
        ushort4 o;
        o.x = bf16u(v.x); o.y = bf16u(v.y); o.z = bf16u(v.z); o.w = bf16u(v.w);
        *reinterpret_cast<ushort4*>(out + i) = o;
    }
}

// ---------------- V transpose: VT[h][d][t] = V[h][t][d], bf16 ----------------
__global__ __launch_bounds__(256) void transpose_v(const float* __restrict__ V,
                                                   u16* __restrict__ VT) {
    __shared__ float tile[32][33];
    int h = blockIdx.z;
    int t0 = blockIdx.x * 32, d0 = blockIdx.y * 32;
    int tx = threadIdx.x & 31, ty = threadIdx.x >> 5;
#pragma unroll
    for (int r = 0; r < 4; ++r) {
        int t = ty + r * 8;
        tile[t][tx] = V[(size_t)h * S_LEN * HD + (size_t)(t0 + t) * HD + d0 + tx];
    }
    __syncthreads();
#pragma unroll
    for (int r = 0; r < 4; ++r) {
        int d = ty + r * 8;
        VT[(size_t)h * HD * S_LEN + (size_t)(d0 + d) * S_LEN + t0 + tx] = bf16u(tile[tx][d]);
    }
}

// ---------------- bf16 NT GEMM, 2-phase dbuf + XCD supertile swizzle --------
template<typename OT>
__global__ __launch_bounds__(256) void gemm_nt(const u16* __restrict__ A,
                                               const u16* __restrict__ B,
                                               OT* __restrict__ C,
                                               int M, int N, int K) {
    __shared__ u16 As[2][128 * 32];
    __shared__ u16 Bs[2][128 * 32];
    const int tid = threadIdx.x;
    const int wid = tid >> 6, lane = tid & 63;

    // XCD supertile swizzle: each XCD gets a compact rectangle of tiles.
    const int gx = gridDim.x, gy = gridDim.y;
    int tx = blockIdx.x, ty = blockIdx.y;
    {
        int total = gx * gy;
        if ((total & 63) == 0 && gx >= 8) {
            int chunk = total >> 3;
            int srows = chunk >> 3;
            if (srows > 0 && (gy % srows) == 0) {
                int bid = blockIdx.y * gx + blockIdx.x;
                int xcd = bid & 7, loc = bid >> 3;
                int nsx = gx >> 3;
                int sqx = xcd % nsx, sqy = xcd / nsx;
                tx = sqx * 8 + (loc & 7);
                ty = sqy * srows + (loc >> 3);
            }
        }
    }
    const int row0 = ty * 128, col0 = tx * 128;
    const int wr = (wid >> 1) * 64, wc = (wid & 1) * 64;

    const int strow = wid * 16 + (lane >> 2);
    const int schunk = (lane & 3) * 8;

    f4 acc[4][4] = {};
    const int fr = lane & 15, fk = (lane >> 4) * 8;

#define GSTAGE(b, k0)                                                             \
    {                                                                             \
        __builtin_amdgcn_global_load_lds(                                         \
            (const GAS void*)(A + (size_t)(row0 + strow) * K + (k0) + schunk),    \
            (LAS void*)(As[b] + wid * 512), 16, 0, 0);                            \
        __builtin_amdgcn_global_load_lds(                                         \
            (const GAS void*)(A + (size_t)(row0 + 64 + strow) * K + (k0) + schunk),\
            (LAS void*)(As[b] + 2048 + wid * 512), 16, 0, 0);                     \
        __builtin_amdgcn_global_load_lds(                                         \
            (const GAS void*)(B + (size_t)(col0 + strow) * K + (k0) + schunk),    \
            (LAS void*)(Bs[b] + wid * 512), 16, 0, 0);                            \
        __builtin_amdgcn_global_load_lds(                                         \
            (const GAS void*)(B + (size_t)(col0 + 64 + strow) * K + (k0) + schunk),\
            (LAS void*)(Bs[b] + 2048 + wid * 512), 16, 0, 0);                     \
    }

    GSTAGE(0, 0);
    __syncthreads();

    const int nk = K >> 5;
    for (int t = 0; t < nk; ++t) {
        const int cur = t & 1;
        if (t + 1 < nk) GSTAGE(cur ^ 1, (t + 1) * 32);

        bh8 af[4], bfv[4];
#pragma unroll
        for (int i = 0; i < 4; ++i) {
            af[i]  = *reinterpret_cast<const bh8*>(&As[cur][(wr + i * 16 + fr) * 32 + fk]);
            bfv[i] = *reinterpret_cast<const bh8*>(&Bs[cur][(wc + i * 16 + fr) * 32 + fk]);
        }
#pragma unroll
        for (int i = 0; i < 4; ++i)
#pragma unroll
            for (int j = 0; j < 4; ++j)
                acc[i][j] = __builtin_amdgcn_mfma_f32_16x16x32_bf16(af[i], bfv[j], acc[i][j], 0, 0, 0);
        __syncthreads();
    }
#undef GSTAGE

    const int orow = (lane >> 4) * 4, ocol = lane & 15;
#pragma unroll
    for (int i = 0; i < 4; ++i)
#pragma unroll
        for (int j = 0; j < 4; ++j)
#pragma unroll
            for (int e = 0; e < 4; ++e) {
                float v = acc[i][j][e];
                size_t off = (size_t)(row0 + wr + i * 16 + orow + e) * N + col0 + wc + j * 16 + ocol;
                if constexpr (__is_same(OT, u16)) C[off] = bf16u(v);
                else C[off] = v;
            }
}

// ---------------- q prep: RMS + partial RoPE + fold SCALE*log2e, bf16 --------
__global__ __launch_bounds__(256) void qprep(const u16* __restrict__ C1b,
                                             const float* __restrict__ cosb,
                                             const float* __restrict__ sinb,
                                             const float* __restrict__ qw,
                                             u16* __restrict__ Qb) {
    constexpr float KS = 0.08838834764831845f * 1.4426950408889634f;
    int wid = threadIdx.x >> 6, lane = threadIdx.x & 63;
    int id = blockIdx.x * 4 + wid;          // (h,s) index
    int h = id >> 11, s = id & 2047;
    const u16* row = C1b + (size_t)s * 4096 + h * 256;
    float v0 = b2f(row[lane]), v1 = b2f(row[lane + 64]);
    float ss = v0 * v0 + v1 * v1;
#pragma unroll
    for (int off = 32; off; off >>= 1) ss += __shfl_xor(ss, off, 64);
    float sc = rsqrtf(ss * (1.f / 128.f) + 1e-6f);
    float q0 = v0 * sc * (1.f + qw[lane]);
    float q1 = v1 * sc * (1.f + qw[lane + 64]);
    float part = __shfl_xor(q0, 32, 64);
    float rot = (lane < 32) ? -part : part;
    float c = cosb[s * 64 + lane], sn = sinb[s * 64 + lane];
    float o0 = q0 * c + rot * sn;
    u16* dst = Qb + (size_t)h * S_LEN * HD + (size_t)s * HD;
    dst[lane] = bf16u(o0 * KS);
    dst[lane + 64] = bf16u(q1 * KS);
}

// ---------------- flash attention, swapped-QK, KV-split ----------------------
// S^T = mfma(K,Q): lane owns one q-row, softmax in-lane, P stays in registers.
// K/V double-buffered via global_load_lds (no staging VGPRs -> no spills).
__global__ __launch_bounds__(256, 2) void attn_kernel(const u16* __restrict__ Qb,
                                                      const u16* __restrict__ Kb,
                                                      const u16* __restrict__ VTb,
                                                      u16* __restrict__ O0p,
                                                      u16* __restrict__ O1p,
                                                      float* __restrict__ M0,
                                                      float* __restrict__ L0,
                                                      float* __restrict__ M1,
                                                      float* __restrict__ L1) {
    __shared__ __align__(16) char buf[65536];          // 64 KiB
    u16* Kt0 = (u16*)buf;                              // [64 kv][128 d]
    u16* Vt0 = (u16*)(buf + 16384);                    // [128 d][64 kv]
    u16* Kt1 = (u16*)(buf + 32768);
    u16* Vt1 = (u16*)(buf + 49152);

    const int tid = threadIdx.x, wid = tid >> 6, lane = tid & 63;
    const int bid = blockIdx.x;          // 0..1023
    const int half = bid & 1;
    const int rest = bid >> 1;
    const int h = rest & 15;
    const int qb = 31 - (rest >> 4);     // LPT: longest dispatched first
    const int q0w = qb * 64 + wid * 16;
    const int h4 = h >> 2;
    const u16* Qh = Qb + (size_t)h * S_LEN * HD;
    const u16* Kh = Kb + (size_t)h4 * S_LEN * HD;
    const u16* Vh = VTb + (size_t)h4 * HD * S_LEN;
    const int fr = lane & 15, hi4 = lane >> 4;
    const int sx = fr & 7;
    constexpr float THR = 11.5f;

    const int nt0 = (qb + 1) >> 1;
    const int tb = half ? nt0 : 0;
    const int te = half ? (qb + 1) : nt0;
    const int qrow = q0w + fr;           // this lane's q-row

    bh8 qf[4];
#pragma unroll
    for (int kb = 0; kb < 4; ++kb)
        qf[kb] = *reinterpret_cast<const bh8*>(&Qh[(size_t)qrow * HD + kb * 32 + hi4 * 8]);

    f4 acc[8] = {};                      // O^T: acc[dt][j] -> d=dt*16+hi4*4+j, q=qrow
    float m_r = -1e30f, l_r = 0.f;

    // stage tile t0 via global_load_lds (pre-swizzled source, linear LDS dest)
#define STAGE(kd, vd, t0)                                                         \
    {                                                                             \
        _Pragma("unroll")                                                         \
        for (int i = 0; i < 4; ++i) {                                             \
            int row = wid * 16 + i * 4 + (lane >> 4);                             \
            int ck = (lane & 15) ^ (row & 7);                                     \
            __builtin_amdgcn_global_load_lds(                                     \
                (const GAS void*)(Kh + (size_t)((t0) + row) * HD + ck * 8),       \
                (LAS void*)((kd) + (wid * 16 + i * 4) * HD), 16, 0, 0);           \
        }                                                                         \
        _Pragma("unroll")                                                         \
        for (int i = 0; i < 4; ++i) {                                             \
            int row = wid * 32 + i * 8 + (lane >> 3);                             \
            int cv = (lane & 7) ^ (row & 7);                                      \
            __builtin_amdgcn_global_load_lds(                                     \
                (const GAS void*)(Vh + (size_t)row * S_LEN + (t0) + cv * 8),      \
                (LAS void*)((vd) + (wid * 32 + i * 8) * KVB), 16, 0, 0);          \
        }                                                                         \
    }

    auto tile_step = [&](int t0, const u16* Ktc, const u16* Vtc, bool masked) {
        // QK^T swapped: z[nf][j] = S^T[kv=t0+nf*16+hi4*4+j][q=qrow] (log2 units)
        f4 z[4];
#pragma unroll
        for (int nf = 0; nf < 4; ++nf) {
            f4 zz = {};
#pragma unroll
            for (int kb = 0; kb < 4; ++kb) {
                bh8 kf = *reinterpret_cast<const bh8*>(
                    &Ktc[(nf * 16 + fr) * HD + (((kb * 4 + hi4) ^ sx) * 8)]);
                zz = __builtin_amdgcn_mfma_f32_16x16x32_bf16(kf, qf[kb], zz, 0, 0, 0);
            }
            z[nf] = zz;
        }
        if (masked) {
#pragma unroll
            for (int nf = 0; nf < 4; ++nf)
#pragma unroll
                for (int j = 0; j < 4; ++j)
                    if (t0 + nf * 16 + hi4 * 4 + j > qrow) z[nf][j] = -3.0e38f;
        }
        // row max: 15 in-lane + 2 shuffles (across hi4 groups)
        float v = z[0][0];
#pragma unroll
        for (int nf = 0; nf < 4; ++nf)
#pragma unroll
            for (int j = 0; j < 4; ++j) v = fmaxf(v, z[nf][j]);
        v = fmaxf(v, __shfl_xor(v, 16, 64));
        v = fmaxf(v, __shfl_xor(v, 32, 64));
        if (__any(v > m_r + THR)) {
            float nm = fmaxf(m_r, v);
            float corr = exp2f(m_r - nm);
            m_r = nm;
            l_r *= corr;
#pragma unroll
            for (int dt = 0; dt < 8; ++dt)
#pragma unroll
                for (int j = 0; j < 4; ++j) acc[dt][j] *= corr;
        }
        // exp + partial l + pack to bf16 (lane keeps its own q-row's P)
        u32 pk[4][2];
#pragma unroll
        for (int nf = 0; nf < 4; ++nf) {
            float p0 = exp2f(z[nf][0] - m_r), p1 = exp2f(z[nf][1] - m_r);
            float p2 = exp2f(z[nf][2] - m_r), p3 = exp2f(z[nf][3] - m_r);
            l_r += (p0 + p1) + (p2 + p3);
            pk[nf][0] = pack2(p0, p1);
            pk[nf][1] = pack2(p2, p3);
        }
        // PV: pa = lane's own 8 p-values per 32-kv block; V^T sigma-permuted reads
#pragma unroll
        for (int kk = 0; kk < 2; ++kk) {
            union { u32 w[4]; bh8 v8; } u;
            u.w[0] = pk[2 * kk][0];     u.w[1] = pk[2 * kk][1];
            u.w[2] = pk[2 * kk + 1][0]; u.w[3] = pk[2 * kk + 1][1];
            bh8 pa = u.v8;
            const int cA = kk * 4 + (hi4 >> 1);
            const int off = (hi4 & 1) * 4;
#pragma unroll
            for (int dt = 0; dt < 8; ++dt) {
                int base = (dt * 16 + fr) * KVB;
                bh4 lo = *reinterpret_cast<const bh4*>(&Vtc[base + ((cA ^ sx) * 8) + off]);
                bh4 hi = *reinterpret_cast<const bh4*>(&Vtc[base + (((cA + 2) ^ sx) * 8) + off]);
                bh8 vf = __builtin_shufflevector(lo, hi, 0, 1, 2, 3, 4, 5, 6, 7);
                acc[dt] = __builtin_amdgcn_mfma_f32_16x16x32_bf16(vf, pa, acc[dt], 0, 0, 0);
            }
        }
    };

    if (tb < te) {
        STAGE(Kt0, Vt0, tb * KVB);
        __syncthreads();
        int cur = 0;
        for (int t = tb; t < te; ++t) {
            if (t + 1 < te) {
                if (cur) STAGE(Kt0, Vt0, (t + 1) * KVB)
                else     STAGE(Kt1, Vt1, (t + 1) * KVB)
            }
            tile_step(t * KVB, cur ? Kt1 : Kt0, cur ? Vt1 : Vt0, t == qb);
            __syncthreads();             // readers done + async stage drained
            cur ^= 1;
        }
    }
#undef STAGE

    // epilogue: reduce l across hi4 groups; transpose O^T via LDS; bf16 partials
    float l_tot = l_r;
    l_tot += __shfl_xor(l_tot, 16, 64);
    l_tot += __shfl_xor(l_tot, 32, 64);

    u16* Op = half ? O1p : O0p;
    float* Mp = half ? M1 : M0;
    float* Lp = half ? L1 : L0;
    if (hi4 == 0) {
        Mp[h * S_LEN + qrow] = m_r;
        Lp[h * S_LEN + qrow] = l_tot;
    }

    float* ep = (float*)buf + wid * (16 * EPS_STRIDE);
#pragma unroll
    for (int dt = 0; dt < 8; ++dt)
#pragma unroll
        for (int j = 0; j < 4; ++j)
            ep[fr * EPS_STRIDE + dt * 16 + hi4 * 4 + j] = acc[dt][j];
    asm volatile("s_waitcnt lgkmcnt(0)" ::: "memory");   // per-wave private region

    const int q_l = lane >> 2;           // 0..15
    const int c0 = (lane & 3) * 32;      // d base
    const float* eprow = ep + q_l * EPS_STRIDE + c0;
    u16* dst = Op + ((size_t)h * S_LEN + (q0w + q_l)) * HD + c0;
#pragma unroll
    for (int i2 = 0; i2 < 4; ++i2) {
        f4 a = *reinterpret_cast<const f4*>(eprow + i2 * 8);
        f4 b = *reinterpret_cast<const f4*>(eprow + i2 * 8 + 4);
        uint4 w;
        w.x = pack2(a[0], a[1]); w.y = pack2(a[2], a[3]);
        w.z = pack2(b[0], b[1]); w.w = pack2(b[2], b[3]);
        *reinterpret_cast<uint4*>(dst + i2 * 8) = w;
    }
}

// ---------------- combine: merge 2 KV-halves, gate, emit bf16 AO -------------
__global__ __launch_bounds__(256) void attn_combine(const u16* __restrict__ O0p,
                                                    const u16* __restrict__ O1p,
                                                    const float* __restrict__ M0,
                                                    const float* __restrict__ L0,
                                                    const float* __restrict__ M1,
                                                    const float* __restrict__ L1,
                                                    const u16* __restrict__ C1b,
                                                    u16* __restrict__ AO) {
    constexpr float L2E = 1.4426950408889634f;
    int idx = blockIdx.x * 256 + threadIdx.x;   // 16*2048*16 total
    int d8 = idx & 15;
    int s  = (idx >> 4) & 2047;
    int h  = idx >> 15;
    int row = h * S_LEN + s;
    float m0 = M0[row], l0 = L0[row], m1 = M1[row], l1 = L1[row];
    float m = fmaxf(m0, m1);
    float a = exp2f(m0 - m), b = exp2f(m1 - m);
    float inv = 1.f / (a * l0 + b * l1);
    bh8 o0 = *reinterpret_cast<const bh8*>(O0p + (size_t)row * HD + d8 * 8);
    bh8 o1 = *reinterpret_cast<const bh8*>(O1p + (size_t)row * HD + d8 * 8);
    bh8 g  = *reinterpret_cast<const bh8*>(C1b + (size_t)s * 4096 + h * 256 + 128 + d8 * 8);
    u32 w[4];
#pragma unroll
    for (int e = 0; e < 4; ++e) {
        float v0 = (a * b2f((u16)o0[2 * e]) + b * b2f((u16)o1[2 * e])) * inv;
        float v1 = (a * b2f((u16)o0[2 * e + 1]) + b * b2f((u16)o1[2 * e + 1])) * inv;
        v0 *= 1.f / (1.f + exp2f(-b2f((u16)g[2 * e]) * L2E));
        v1 *= 1.f / (1.f + exp2f(-b2f((u16)g[2 * e + 1]) * L2E));
        w[e] = pack2(v0, v1);
    }
    uint4 ww = {w[0], w[1], w[2], w[3]};
    *reinterpret_cast<uint4*>(AO + (size_t)s * D_MODEL + h * HD + d8 * 8) = ww;
}

extern "C" void kernel_launch(void* const* d_in, const int* in_sizes, int n_in,
                              void* d_out, int out_size, void* d_ws, size_t ws_size,
                              hipStream_t stream) {
    const float* hs   = (const float*)d_in[0];
    const float* Kc   = (const float*)d_in[1];
    const float* Vc   = (const float*)d_in[2];
    const float* cosb = (const float*)d_in[3];
    const float* sinb = (const float*)d_in[4];
    const float* Wq   = (const float*)d_in[6];
    const float* Wo   = (const float*)d_in[9];
    const float* qw   = (const float*)d_in[10];
    float* out = (float*)d_out;

    char* ws = (char*)d_ws;
    u16*   x_bf  = (u16*)ws;                          // 8 MiB  (dead after gemm1)
    u16*   Wq_bf = (u16*)(ws + (8u << 20));           // 16 MiB (dead after gemm1)
    u16*   Wo_bf = (u16*)(ws + (24u << 20));          // 8 MiB  (live till gemm2)
    u16*   K_bf  = (u16*)(ws + (32u << 20));          // 2 MiB
    u16*   VT_bf = (u16*)(ws + (34u << 20));          // 2 MiB
    u16*   C1b   = (u16*)(ws + (36u << 20));          // 16 MiB bf16 (q|gate)
    u16*   Qb    = (u16*)(ws + (68u << 20));          // 8 MiB
    u16*   AO    = (u16*)(ws + (76u << 20));          // 8 MiB
    // attn partials overlay the dead x_bf/Wq_bf region:
    u16*   O0p   = (u16*)ws;                          // 8 MiB
    u16*   O1p   = (u16*)(ws + (8u << 20));           // 8 MiB
    float* M0    = (float*)(ws + (16u << 20));        // 128 KiB each
    float* L0    = M0 + NH * S_LEN;
    float* M1    = L0 + NH * S_LEN;
    float* L1    = M1 + NH * S_LEN;

    cvt_bf16<<<4096, 256, 0, stream>>>(hs, x_bf, 2048 * 2048);
    cvt_bf16<<<8192, 256, 0, stream>>>(Wq, Wq_bf, 4096 * 2048);
    cvt_bf16<<<4096, 256, 0, stream>>>(Wo, Wo_bf, 2048 * 2048);
    cvt_bf16<<<1024, 256, 0, stream>>>(Kc, K_bf, NKVH * S_LEN * HD);
    transpose_v<<<dim3(64, 4, NKVH), 256, 0, stream>>>(Vc, VT_bf);

    gemm_nt<u16><<<dim3(32, 16), 256, 0, stream>>>(x_bf, Wq_bf, C1b, 2048, 4096, 2048);
    qprep<<<8192, 256, 0, stream>>>(C1b, cosb, sinb, qw, Qb);
    attn_kernel<<<1024, 256, 0, stream>>>(Qb, K_bf, VT_bf, O0p, O1p, M0, L0, M1, L1);
    attn_combine<<<2048, 256, 0, stream>>>(O0p, O1p, M0, L0, M1, L1, C1b, AO);
    gemm_nt<float><<<dim3(16, 16), 256, 0, stream>>>(AO, Wo_bf, out, 2048, 2048, 2048);
}

// Round 9
// 161.918 us; speedup vs baseline: 1.1496x; 1.0646x over previous
//
#include <hip/hip_runtime.h>
#include <hip/hip_bf16.h>

#define S_LEN 2048
#define D_MODEL 2048
#define NH 16
#define NKVH 4
#define HD 128
#define KVB 64
#define EPS_STRIDE 132   // epilogue LDS row stride (f32), 4-aligned, non-pow2

typedef __attribute__((ext_vector_type(8))) short bh8;   // 8 bf16
typedef __attribute__((ext_vector_type(4))) short bh4;   // 4 bf16
typedef __attribute__((ext_vector_type(4))) float f4;
typedef unsigned short u16;
typedef unsigned int u32;

#define GAS __attribute__((address_space(1)))
#define LAS __attribute__((address_space(3)))

__device__ __forceinline__ u16 bf16u(float x) {
    __hip_bfloat16 h = __float2bfloat16(x);
    return __builtin_bit_cast(u16, h);
}
__device__ __forceinline__ float b2f(u16 u) {
    return __builtin_bit_cast(float, (u32)u << 16);
}
__device__ __forceinline__ u32 pack2(float a, float b) {
    return (u32)bf16u(a) | ((u32)bf16u(b) << 16);
}

// ---------------- fused fp32 -> bf16 conversion (4 regions, 1 launch) --------
__device__ __forceinline__ void cvt_region(const float* __restrict__ in,
                                           u16* __restrict__ out, int n,
                                           int gtid, int gthreads) {
    for (int i = gtid * 4; i < n; i += gthreads * 4) {
        float4 v = *reinterpret_cast<const float4*>(in + i);
        ushort4 o;
        o.x = bf16u(v.x); o.y = bf16u(v.y); o.z = bf16u(v.z); o.w = bf16u(v.w);
        *reinterpret_cast<ushort4*>(out + i) = o;
    }
}
__global__ __launch_bounds__(256) void cvt_all(const float* __restrict__ a, u16* __restrict__ oa, int na,
                                               const float* __restrict__ b, u16* __restrict__ ob, int nb,
                                               const float* __restrict__ c, u16* __restrict__ oc, int nc,
                                               const float* __restrict__ d, u16* __restrict__ od, int nd) {
    int gtid = blockIdx.x * 256 + threadIdx.x;
    int gthreads = gridDim.x * 256;
    cvt_region(a, oa, na, gtid, gthreads);
    cvt_region(b, ob, nb, gtid, gthreads);
    cvt_region(c, oc, nc, gtid, gthreads);
    cvt_region(d, od, nd, gtid, gthreads);
}

// ---------------- V transpose: VT[h][d][t] = V[h][t][d], bf16 ----------------
__global__ __launch_bounds__(256) void transpose_v(const float* __restrict__ V,
                                                   u16* __restrict__ VT) {
    __shared__ float tile[32][33];
    int h = blockIdx.z;
    int t0 = blockIdx.x * 32, d0 = blockIdx.y * 32;
    int tx = threadIdx.x & 31, ty = threadIdx.x >> 5;
#pragma unroll
    for (int r = 0; r < 4; ++r) {
        int t = ty + r * 8;
        tile[t][tx] = V[(size_t)h * S_LEN * HD + (size_t)(t0 + t) * HD + d0 + tx];
    }
    __syncthreads();
#pragma unroll
    for (int r = 0; r < 4; ++r) {
        int d = ty + r * 8;
        VT[(size_t)h * HD * S_LEN + (size_t)(d0 + d) * S_LEN + t0 + tx] = bf16u(tile[tx][d]);
    }
}

// ---------------- bf16 NT GEMM, 128x128, 2-phase dbuf + XCD swizzle ---------
template<typename OT>
__global__ __launch_bounds__(256) void gemm_nt(const u16* __restrict__ A,
                                               const u16* __restrict__ B,
                                               OT* __restrict__ C,
                                               int M, int N, int K) {
    __shared__ u16 As[2][128 * 32];
    __shared__ u16 Bs[2][128 * 32];
    const int tid = threadIdx.x;
    const int wid = tid >> 6, lane = tid & 63;

    const int gx = gridDim.x, gy = gridDim.y;
    int tx = blockIdx.x, ty = blockIdx.y;
    {
        int total = gx * gy;
        if ((total & 63) == 0 && gx >= 8) {
            int chunk = total >> 3;
            int srows = chunk >> 3;
            if (srows > 0 && (gy % srows) == 0) {
                int bid = blockIdx.y * gx + blockIdx.x;
                int xcd = bid & 7, loc = bid >> 3;
                int nsx = gx >> 3;
                int sqx = xcd % nsx, sqy = xcd / nsx;
                tx = sqx * 8 + (loc & 7);
                ty = sqy * srows + (loc >> 3);
            }
        }
    }
    const int row0 = ty * 128, col0 = tx * 128;
    const int wr = (wid >> 1) * 64, wc = (wid & 1) * 64;

    const int strow = wid * 16 + (lane >> 2);
    const int schunk = (lane & 3) * 8;

    f4 acc[4][4] = {};
    const int fr = lane & 15, fk = (lane >> 4) * 8;

#define GSTAGE(b, k0)                                                             \
    {                                                                             \
        __builtin_amdgcn_global_load_lds(                                         \
            (const GAS void*)(A + (size_t)(row0 + strow) * K + (k0) + schunk),    \
            (LAS void*)(As[b] + wid * 512), 16, 0, 0);                            \
        __builtin_amdgcn_global_load_lds(                                         \
            (const GAS void*)(A + (size_t)(row0 + 64 + strow) * K + (k0) + schunk),\
            (LAS void*)(As[b] + 2048 + wid * 512), 16, 0, 0);                     \
        __builtin_amdgcn_global_load_lds(                                         \
            (const GAS void*)(B + (size_t)(col0 + strow) * K + (k0) + schunk),    \
            (LAS void*)(Bs[b] + wid * 512), 16, 0, 0);                            \
        __builtin_amdgcn_global_load_lds(                                         \
            (const GAS void*)(B + (size_t)(col0 + 64 + strow) * K + (k0) + schunk),\
            (LAS void*)(Bs[b] + 2048 + wid * 512), 16, 0, 0);                     \
    }

    GSTAGE(0, 0);
    __syncthreads();

    const int nk = K >> 5;
    for (int t = 0; t < nk; ++t) {
        const int cur = t & 1;
        if (t + 1 < nk) GSTAGE(cur ^ 1, (t + 1) * 32);

        bh8 af[4], bfv[4];
#pragma unroll
        for (int i = 0; i < 4; ++i) {
            af[i]  = *reinterpret_cast<const bh8*>(&As[cur][(wr + i * 16 + fr) * 32 + fk]);
            bfv[i] = *reinterpret_cast<const bh8*>(&Bs[cur][(wc + i * 16 + fr) * 32 + fk]);
        }
#pragma unroll
        for (int i = 0; i < 4; ++i)
#pragma unroll
            for (int j = 0; j < 4; ++j)
                acc[i][j] = __builtin_amdgcn_mfma_f32_16x16x32_bf16(af[i], bfv[j], acc[i][j], 0, 0, 0);
        __syncthreads();
    }
#undef GSTAGE

    const int orow = (lane >> 4) * 4, ocol = lane & 15;
#pragma unroll
    for (int i = 0; i < 4; ++i)
#pragma unroll
        for (int j = 0; j < 4; ++j)
#pragma unroll
            for (int e = 0; e < 4; ++e) {
                float v = acc[i][j][e];
                size_t off = (size_t)(row0 + wr + i * 16 + orow + e) * N + col0 + wc + j * 16 + ocol;
                if constexpr (__is_same(OT, u16)) C[off] = bf16u(v);
                else C[off] = v;
            }
}

// ---------------- bf16 NT GEMM, 128x64 tile (2 blocks/CU for small grids) ----
template<typename OT>
__global__ __launch_bounds__(256) void gemm_nt64(const u16* __restrict__ A,
                                                 const u16* __restrict__ B,
                                                 OT* __restrict__ C,
                                                 int M, int N, int K) {
    __shared__ u16 As[2][128 * 32];
    __shared__ u16 Bs[2][64 * 32];
    const int tid = threadIdx.x;
    const int wid = tid >> 6, lane = tid & 63;

    const int gx = gridDim.x, gy = gridDim.y;
    int tx = blockIdx.x, ty = blockIdx.y;
    {
        int total = gx * gy;
        if ((total & 63) == 0 && gx >= 8) {
            int chunk = total >> 3;
            int srows = chunk >> 3;
            if (srows > 0 && (gy % srows) == 0) {
                int bid = blockIdx.y * gx + blockIdx.x;
                int xcd = bid & 7, loc = bid >> 3;
                int nsx = gx >> 3;
                int sqx = xcd % nsx, sqy = xcd / nsx;
                tx = sqx * 8 + (loc & 7);
                ty = sqy * srows + (loc >> 3);
            }
        }
    }
    const int row0 = ty * 128, col0 = tx * 64;
    const int wr = (wid >> 1) * 64, wc = (wid & 1) * 32;

    const int strow = wid * 16 + (lane >> 2);
    const int schunk = (lane & 3) * 8;

    f4 acc[4][2] = {};
    const int fr = lane & 15, fk = (lane >> 4) * 8;

#define GSTAGE64(b, k0)                                                           \
    {                                                                             \
        __builtin_amdgcn_global_load_lds(                                         \
            (const GAS void*)(A + (size_t)(row0 + strow) * K + (k0) + schunk),    \
            (LAS void*)(As[b] + wid * 512), 16, 0, 0);                            \
        __builtin_amdgcn_global_load_lds(                                         \
            (const GAS void*)(A + (size_t)(row0 + 64 + strow) * K + (k0) + schunk),\
            (LAS void*)(As[b] + 2048 + wid * 512), 16, 0, 0);                     \
        __builtin_amdgcn_global_load_lds(                                         \
            (const GAS void*)(B + (size_t)(col0 + strow) * K + (k0) + schunk),    \
            (LAS void*)(Bs[b] + wid * 512), 16, 0, 0);                            \
    }

    GSTAGE64(0, 0);
    __syncthreads();

    const int nk = K >> 5;
    for (int t = 0; t < nk; ++t) {
        const int cur = t & 1;
        if (t + 1 < nk) GSTAGE64(cur ^ 1, (t + 1) * 32);

        bh8 af[4], bfv[2];
#pragma unroll
        for (int i = 0; i < 4; ++i)
            af[i] = *reinterpret_cast<const bh8*>(&As[cur][(wr + i * 16 + fr) * 32 + fk]);
#pragma unroll
        for (int j = 0; j < 2; ++j)
            bfv[j] = *reinterpret_cast<const bh8*>(&Bs[cur][(wc + j * 16 + fr) * 32 + fk]);
#pragma unroll
        for (int i = 0; i < 4; ++i)
#pragma unroll
            for (int j = 0; j < 2; ++j)
                acc[i][j] = __builtin_amdgcn_mfma_f32_16x16x32_bf16(af[i], bfv[j], acc[i][j], 0, 0, 0);
        __syncthreads();
    }
#undef GSTAGE64

    const int orow = (lane >> 4) * 4, ocol = lane & 15;
#pragma unroll
    for (int i = 0; i < 4; ++i)
#pragma unroll
        for (int j = 0; j < 2; ++j)
#pragma unroll
            for (int e = 0; e < 4; ++e) {
                float v = acc[i][j][e];
                size_t off = (size_t)(row0 + wr + i * 16 + orow + e) * N + col0 + wc + j * 16 + ocol;
                if constexpr (__is_same(OT, u16)) C[off] = bf16u(v);
                else C[off] = v;
            }
}

// ---------------- q prep: RMS + partial RoPE + fold SCALE*log2e, bf16 --------
__global__ __launch_bounds__(256) void qprep(const u16* __restrict__ C1b,
                                             const float* __restrict__ cosb,
                                             const float* __restrict__ sinb,
                                             const float* __restrict__ qw,
                                             u16* __restrict__ Qb) {
    constexpr float KS = 0.08838834764831845f * 1.4426950408889634f;
    int wid = threadIdx.x >> 6, lane = threadIdx.x & 63;
    int id = blockIdx.x * 4 + wid;          // (h,s) index
    int h = id >> 11, s = id & 2047;
    const u16* row = C1b + (size_t)s * 4096 + h * 256;
    float v0 = b2f(row[lane]), v1 = b2f(row[lane + 64]);
    float ss = v0 * v0 + v1 * v1;
#pragma unroll
    for (int off = 32; off; off >>= 1) ss += __shfl_xor(ss, off, 64);
    float sc = rsqrtf(ss * (1.f / 128.f) + 1e-6f);
    float q0 = v0 * sc * (1.f + qw[lane]);
    float q1 = v1 * sc * (1.f + qw[lane + 64]);
    float part = __shfl_xor(q0, 32, 64);
    float rot = (lane < 32) ? -part : part;
    float c = cosb[s * 64 + lane], sn = sinb[s * 64 + lane];
    float o0 = q0 * c + rot * sn;
    u16* dst = Qb + (size_t)h * S_LEN * HD + (size_t)s * HD;
    dst[lane] = bf16u(o0 * KS);
    dst[lane + 64] = bf16u(q1 * KS);
}

// ---------------- flash attention, swapped-QK, KV-split ----------------------
__global__ __launch_bounds__(256, 2) void attn_kernel(const u16* __restrict__ Qb,
                                                      const u16* __restrict__ Kb,
                                                      const u16* __restrict__ VTb,
                                                      u16* __restrict__ O0p,
                                                      u16* __restrict__ O1p,
                                                      float* __restrict__ M0,
                                                      float* __restrict__ L0,
                                                      float* __restrict__ M1,
                                                      float* __restrict__ L1) {
    __shared__ __align__(16) char buf[65536];          // 64 KiB
    u16* Kt0 = (u16*)buf;                              // [64 kv][128 d]
    u16* Vt0 = (u16*)(buf + 16384);                    // [128 d][64 kv]
    u16* Kt1 = (u16*)(buf + 32768);
    u16* Vt1 = (u16*)(buf + 49152);

    const int tid = threadIdx.x, wid = tid >> 6, lane = tid & 63;
    const int bid = blockIdx.x;          // 0..1023
    const int half = bid & 1;
    const int rest = bid >> 1;
    const int h = rest & 15;
    const int qb = 31 - (rest >> 4);     // LPT: longest dispatched first
    const int q0w = qb * 64 + wid * 16;
    const int h4 = h >> 2;
    const u16* Qh = Qb + (size_t)h * S_LEN * HD;
    const u16* Kh = Kb + (size_t)h4 * S_LEN * HD;
    const u16* Vh = VTb + (size_t)h4 * HD * S_LEN;
    const int fr = lane & 15, hi4 = lane >> 4;
    const int sx = fr & 7;
    constexpr float THR = 11.5f;

    const int nt0 = (qb + 1) >> 1;
    const int tb = half ? nt0 : 0;
    const int te = half ? (qb + 1) : nt0;
    const int qrow = q0w + fr;           // this lane's q-row

    bh8 qf[4];
#pragma unroll
    for (int kb = 0; kb < 4; ++kb)
        qf[kb] = *reinterpret_cast<const bh8*>(&Qh[(size_t)qrow * HD + kb * 32 + hi4 * 8]);

    f4 acc[8] = {};                      // O^T: acc[dt][j] -> d=dt*16+hi4*4+j, q=qrow
    float m_r = -1e30f, l_r = 0.f;

#define STAGE(kd, vd, t0)                                                         \
    {                                                                             \
        _Pragma("unroll")                                                         \
        for (int i = 0; i < 4; ++i) {                                             \
            int row = wid * 16 + i * 4 + (lane >> 4);                             \
            int ck = (lane & 15) ^ (row & 7);                                     \
            __builtin_amdgcn_global_load_lds(                                     \
                (const GAS void*)(Kh + (size_t)((t0) + row) * HD + ck * 8),       \
                (LAS void*)((kd) + (wid * 16 + i * 4) * HD), 16, 0, 0);           \
        }                                                                         \
        _Pragma("unroll")                                                         \
        for (int i = 0; i < 4; ++i) {                                             \
            int row = wid * 32 + i * 8 + (lane >> 3);                             \
            int cv = (lane & 7) ^ (row & 7);                                      \
            __builtin_amdgcn_global_load_lds(                                     \
                (const GAS void*)(Vh + (size_t)row * S_LEN + (t0) + cv * 8),      \
                (LAS void*)((vd) + (wid * 32 + i * 8) * KVB), 16, 0, 0);          \
        }                                                                         \
    }

    auto tile_step = [&](int t0, const u16* Ktc, const u16* Vtc, bool masked) {
        f4 z[4];
#pragma unroll
        for (int nf = 0; nf < 4; ++nf) {
            f4 zz = {};
#pragma unroll
            for (int kb = 0; kb < 4; ++kb) {
                bh8 kf = *reinterpret_cast<const bh8*>(
                    &Ktc[(nf * 16 + fr) * HD + (((kb * 4 + hi4) ^ sx) * 8)]);
                zz = __builtin_amdgcn_mfma_f32_16x16x32_bf16(kf, qf[kb], zz, 0, 0, 0);
            }
            z[nf] = zz;
        }
        if (masked) {
#pragma unroll
            for (int nf = 0; nf < 4; ++nf)
#pragma unroll
                for (int j = 0; j < 4; ++j)
                    if (t0 + nf * 16 + hi4 * 4 + j > qrow) z[nf][j] = -3.0e38f;
        }
        float v = z[0][0];
#pragma unroll
        for (int nf = 0; nf < 4; ++nf)
#pragma unroll
            for (int j = 0; j < 4; ++j) v = fmaxf(v, z[nf][j]);
        v = fmaxf(v, __shfl_xor(v, 16, 64));
        v = fmaxf(v, __shfl_xor(v, 32, 64));
        if (__any(v > m_r + THR)) {
            float nm = fmaxf(m_r, v);
            float corr = exp2f(m_r - nm);
            m_r = nm;
            l_r *= corr;
#pragma unroll
            for (int dt = 0; dt < 8; ++dt)
#pragma unroll
                for (int j = 0; j < 4; ++j) acc[dt][j] *= corr;
        }
        u32 pk[4][2];
#pragma unroll
        for (int nf = 0; nf < 4; ++nf) {
            float p0 = exp2f(z[nf][0] - m_r), p1 = exp2f(z[nf][1] - m_r);
            float p2 = exp2f(z[nf][2] - m_r), p3 = exp2f(z[nf][3] - m_r);
            l_r += (p0 + p1) + (p2 + p3);
            pk[nf][0] = pack2(p0, p1);
            pk[nf][1] = pack2(p2, p3);
        }
#pragma unroll
        for (int kk = 0; kk < 2; ++kk) {
            union { u32 w[4]; bh8 v8; } u;
            u.w[0] = pk[2 * kk][0];     u.w[1] = pk[2 * kk][1];
            u.w[2] = pk[2 * kk + 1][0]; u.w[3] = pk[2 * kk + 1][1];
            bh8 pa = u.v8;
            const int cA = kk * 4 + (hi4 >> 1);
            const int off = (hi4 & 1) * 4;
#pragma unroll
            for (int dt = 0; dt < 8; ++dt) {
                int base = (dt * 16 + fr) * KVB;
                bh4 lo = *reinterpret_cast<const bh4*>(&Vtc[base + ((cA ^ sx) * 8) + off]);
                bh4 hi = *reinterpret_cast<const bh4*>(&Vtc[base + (((cA + 2) ^ sx) * 8) + off]);
                bh8 vf = __builtin_shufflevector(lo, hi, 0, 1, 2, 3, 4, 5, 6, 7);
                acc[dt] = __builtin_amdgcn_mfma_f32_16x16x32_bf16(vf, pa, acc[dt], 0, 0, 0);
            }
        }
    };

    if (tb < te) {
        STAGE(Kt0, Vt0, tb * KVB);
        __syncthreads();
        int cur = 0;
        for (int t = tb; t < te; ++t) {
            if (t + 1 < te) {
                if (cur) STAGE(Kt0, Vt0, (t + 1) * KVB)
                else     STAGE(Kt1, Vt1, (t + 1) * KVB)
            }
            tile_step(t * KVB, cur ? Kt1 : Kt0, cur ? Vt1 : Vt0, t == qb);
            __syncthreads();             // readers done + async stage drained
            cur ^= 1;
        }
    }
#undef STAGE

    float l_tot = l_r;
    l_tot += __shfl_xor(l_tot, 16, 64);
    l_tot += __shfl_xor(l_tot, 32, 64);

    u16* Op = half ? O1p : O0p;
    float* Mp = half ? M1 : M0;
    float* Lp = half ? L1 : L0;
    if (hi4 == 0) {
        Mp[h * S_LEN + qrow] = m_r;
        Lp[h * S_LEN + qrow] = l_tot;
    }

    float* ep = (float*)buf + wid * (16 * EPS_STRIDE);
#pragma unroll
    for (int dt = 0; dt < 8; ++dt)
#pragma unroll
        for (int j = 0; j < 4; ++j)
            ep[fr * EPS_STRIDE + dt * 16 + hi4 * 4 + j] = acc[dt][j];
    asm volatile("s_waitcnt lgkmcnt(0)" ::: "memory");   // per-wave private region

    const int q_l = lane >> 2;           // 0..15
    const int c0 = (lane & 3) * 32;      // d base
    const float* eprow = ep + q_l * EPS_STRIDE + c0;
    u16* dst = Op + ((size_t)h * S_LEN + (q0w + q_l)) * HD + c0;
#pragma unroll
    for (int i2 = 0; i2 < 4; ++i2) {
        f4 a = *reinterpret_cast<const f4*>(eprow + i2 * 8);
        f4 b = *reinterpret_cast<const f4*>(eprow + i2 * 8 + 4);
        uint4 w;
        w.x = pack2(a[0], a[1]); w.y = pack2(a[2], a[3]);
        w.z = pack2(b[0], b[1]); w.w = pack2(b[2], b[3]);
        *reinterpret_cast<uint4*>(dst + i2 * 8) = w;
    }
}

// ---------------- combine: merge 2 KV-halves, gate, emit bf16 AO -------------
__global__ __launch_bounds__(256) void attn_combine(const u16* __restrict__ O0p,
                                                    const u16* __restrict__ O1p,
                                                    const float* __restrict__ M0,
                                                    const float* __restrict__ L0,
                                                    const float* __restrict__ M1,
                                                    const float* __restrict__ L1,
                                                    const u16* __restrict__ C1b,
                                                    u16* __restrict__ AO) {
    constexpr float L2E = 1.4426950408889634f;
    int idx = blockIdx.x * 256 + threadIdx.x;   // 16*2048*16 total
    int d8 = idx & 15;
    int s  = (idx >> 4) & 2047;
    int h  = idx >> 15;
    int row = h * S_LEN + s;
    float m0 = M0[row], l0 = L0[row], m1 = M1[row], l1 = L1[row];
    float m = fmaxf(m0, m1);
    float a = exp2f(m0 - m), b = exp2f(m1 - m);
    float inv = 1.f / (a * l0 + b * l1);
    bh8 o0 = *reinterpret_cast<const bh8*>(O0p + (size_t)row * HD + d8 * 8);
    bh8 o1 = *reinterpret_cast<const bh8*>(O1p + (size_t)row * HD + d8 * 8);
    bh8 g  = *reinterpret_cast<const bh8*>(C1b + (size_t)s * 4096 + h * 256 + 128 + d8 * 8);
    u32 w[4];
#pragma unroll
    for (int e = 0; e < 4; ++e) {
        float v0 = (a * b2f((u16)o0[2 * e]) + b * b2f((u16)o1[2 * e])) * inv;
        float v1 = (a * b2f((u16)o0[2 * e + 1]) + b * b2f((u16)o1[2 * e + 1])) * inv;
        v0 *= 1.f / (1.f + exp2f(-b2f((u16)g[2 * e]) * L2E));
        v1 *= 1.f / (1.f + exp2f(-b2f((u16)g[2 * e + 1]) * L2E));
        w[e] = pack2(v0, v1);
    }
    uint4 ww = {w[0], w[1], w[2], w[3]};
    *reinterpret_cast<uint4*>(AO + (size_t)s * D_MODEL + h * HD + d8 * 8) = ww;
}

extern "C" void kernel_launch(void* const* d_in, const int* in_sizes, int n_in,
                              void* d_out, int out_size, void* d_ws, size_t ws_size,
                              hipStream_t stream) {
    const float* hs   = (const float*)d_in[0];
    const float* Kc   = (const float*)d_in[1];
    const float* Vc   = (const float*)d_in[2];
    const float* cosb = (const float*)d_in[3];
    const float* sinb = (const float*)d_in[4];
    const float* Wq   = (const float*)d_in[6];
    const float* Wo   = (const float*)d_in[9];
    const float* qw   = (const float*)d_in[10];
    float* out = (float*)d_out;

    char* ws = (char*)d_ws;
    u16*   x_bf  = (u16*)ws;                          // 8 MiB  (dead after gemm1)
    u16*   Wq_bf = (u16*)(ws + (8u << 20));           // 16 MiB (dead after gemm1)
    u16*   Wo_bf = (u16*)(ws + (24u << 20));          // 8 MiB  (live till gemm2)
    u16*   K_bf  = (u16*)(ws + (32u << 20));          // 2 MiB
    u16*   VT_bf = (u16*)(ws + (34u << 20));          // 2 MiB
    u16*   C1b   = (u16*)(ws + (36u << 20));          // 16 MiB bf16 (q|gate)
    u16*   Qb    = (u16*)(ws + (68u << 20));          // 8 MiB
    u16*   AO    = (u16*)(ws + (76u << 20));          // 8 MiB
    // attn partials overlay the dead x_bf/Wq_bf region:
    u16*   O0p   = (u16*)ws;                          // 8 MiB
    u16*   O1p   = (u16*)(ws + (8u << 20));           // 8 MiB
    float* M0    = (float*)(ws + (16u << 20));        // 128 KiB each
    float* L0    = M0 + NH * S_LEN;
    float* M1    = L0 + NH * S_LEN;
    float* L1    = M1 + NH * S_LEN;

    cvt_all<<<2048, 256, 0, stream>>>(hs, x_bf, 2048 * 2048,
                                      Wq, Wq_bf, 4096 * 2048,
                                      Wo, Wo_bf, 2048 * 2048,
                                      Kc, K_bf, NKVH * S_LEN * HD);
    transpose_v<<<dim3(64, 4, NKVH), 256, 0, stream>>>(Vc, VT_bf);

    gemm_nt<u16><<<dim3(32, 16), 256, 0, stream>>>(x_bf, Wq_bf, C1b, 2048, 4096, 2048);
    qprep<<<8192, 256, 0, stream>>>(C1b, cosb, sinb, qw, Qb);
    attn_kernel<<<1024, 256, 0, stream>>>(Qb, K_bf, VT_bf, O0p, O1p, M0, L0, M1, L1);
    attn_combine<<<2048, 256, 0, stream>>>(O0p, O1p, M0, L0, M1, L1, C1b, AO);
    gemm_nt64<float><<<dim3(32, 16), 256, 0, stream>>>(AO, Wo_bf, out, 2048, 2048, 2048);
}

// Round 10
// 146.700 us; speedup vs baseline: 1.2688x; 1.1037x over previous
//
#include <hip/hip_runtime.h>
#include <hip/hip_bf16.h>

#define S_LEN 2048
#define D_MODEL 2048
#define NH 16
#define NKVH 4
#define HD 128
#define KVB 64
#define EPS_STRIDE 132   // epilogue LDS row stride (f32), 4-aligned, non-pow2

typedef __attribute__((ext_vector_type(8))) short bh8;   // 8 bf16
typedef __attribute__((ext_vector_type(4))) short bh4;   // 4 bf16
typedef __attribute__((ext_vector_type(4))) float f4;
typedef unsigned short u16;
typedef unsigned int u32;

#define GAS __attribute__((address_space(1)))
#define LAS __attribute__((address_space(3)))

__device__ __forceinline__ u16 bf16u(float x) {
    __hip_bfloat16 h = __float2bfloat16(x);
    return __builtin_bit_cast(u16, h);
}
__device__ __forceinline__ float b2f(u16 u) {
    return __builtin_bit_cast(float, (u32)u << 16);
}
__device__ __forceinline__ u32 pack2(float a, float b) {
    return (u32)bf16u(a) | ((u32)bf16u(b) << 16);
}

// ---------------- fused fp32 -> bf16 conversion (4 regions, 1 launch) --------
__device__ __forceinline__ void cvt_region(const float* __restrict__ in,
                                           u16* __restrict__ out, int n,
                                           int gtid, int gthreads) {
    for (int i = gtid * 4; i < n; i += gthreads * 4) {
        float4 v = *reinterpret_cast<const float4*>(in + i);
        ushort4 o;
        o.x = bf16u(v.x); o.y = bf16u(v.y); o.z = bf16u(v.z); o.w = bf16u(v.w);
        *reinterpret_cast<ushort4*>(out + i) = o;
    }
}
__global__ __launch_bounds__(256) void cvt_all(const float* __restrict__ a, u16* __restrict__ oa, int na,
                                               const float* __restrict__ b, u16* __restrict__ ob, int nb,
                                               const float* __restrict__ c, u16* __restrict__ oc, int nc,
                                               const float* __restrict__ d, u16* __restrict__ od, int nd) {
    int gtid = blockIdx.x * 256 + threadIdx.x;
    int gthreads = gridDim.x * 256;
    cvt_region(a, oa, na, gtid, gthreads);
    cvt_region(b, ob, nb, gtid, gthreads);
    cvt_region(c, oc, nc, gtid, gthreads);
    cvt_region(d, od, nd, gtid, gthreads);
}

// ---------------- V transpose: VT[h][d][t] = V[h][t][d], bf16 ----------------
__global__ __launch_bounds__(256) void transpose_v(const float* __restrict__ V,
                                                   u16* __restrict__ VT) {
    __shared__ float tile[32][33];
    int h = blockIdx.z;
    int t0 = blockIdx.x * 32, d0 = blockIdx.y * 32;
    int tx = threadIdx.x & 31, ty = threadIdx.x >> 5;
#pragma unroll
    for (int r = 0; r < 4; ++r) {
        int t = ty + r * 8;
        tile[t][tx] = V[(size_t)h * S_LEN * HD + (size_t)(t0 + t) * HD + d0 + tx];
    }
    __syncthreads();
#pragma unroll
    for (int r = 0; r < 4; ++r) {
        int d = ty + r * 8;
        VT[(size_t)h * HD * S_LEN + (size_t)(d0 + d) * S_LEN + t0 + tx] = bf16u(tile[tx][d]);
    }
}

// -------- bf16 NT GEMM, 128x128, BK=64, dbuf, XOR-swizzled LDS ---------------
template<typename OT>
__global__ __launch_bounds__(256) void gemm_nt(const u16* __restrict__ A,
                                               const u16* __restrict__ B,
                                               OT* __restrict__ C,
                                               int M, int N, int K) {
    __shared__ u16 As[2][128 * 64];      // 32 KiB
    __shared__ u16 Bs[2][128 * 64];      // 32 KiB  (total 64 KiB)
    const int tid = threadIdx.x;
    const int wid = tid >> 6, lane = tid & 63;

    const int gx = gridDim.x, gy = gridDim.y;
    int tx = blockIdx.x, ty = blockIdx.y;
    {
        int total = gx * gy;
        if ((total & 63) == 0 && gx >= 8) {
            int chunk = total >> 3;
            int srows = chunk >> 3;
            if (srows > 0 && (gy % srows) == 0) {
                int bid = blockIdx.y * gx + blockIdx.x;
                int xcd = bid & 7, loc = bid >> 3;
                int nsx = gx >> 3;
                int sqx = xcd % nsx, sqy = xcd / nsx;
                tx = sqx * 8 + (loc & 7);
                ty = sqy * srows + (loc >> 3);
            }
        }
    }
    const int row0 = ty * 128, col0 = tx * 128;
    const int wr = (wid >> 1) * 64, wc = (wid & 1) * 64;

    f4 acc[4][4] = {};
    const int fr = lane & 15, hi4 = lane >> 4;
    const int sx = fr & 7;

    // stage with pre-swizzled source chunks (ck = chunk ^ row&7), linear LDS dest
#define GSTAGE(b, k0)                                                             \
    {                                                                             \
        _Pragma("unroll")                                                         \
        for (int i = 0; i < 4; ++i) {                                             \
            int rb = i * 32 + wid * 8;                                            \
            int row = rb + (lane >> 3);                                           \
            int ck = (lane & 7) ^ (lane >> 3);                                    \
            __builtin_amdgcn_global_load_lds(                                     \
                (const GAS void*)(A + (size_t)(row0 + row) * K + (k0) + ck * 8),  \
                (LAS void*)(As[b] + rb * 64), 16, 0, 0);                          \
            __builtin_amdgcn_global_load_lds(                                     \
                (const GAS void*)(B + (size_t)(col0 + row) * K + (k0) + ck * 8),  \
                (LAS void*)(Bs[b] + rb * 64), 16, 0, 0);                          \
        }                                                                         \
    }

    GSTAGE(0, 0);
    __syncthreads();

    const int nk = K >> 6;
    for (int t = 0; t < nk; ++t) {
        const int cur = t & 1;
        if (t + 1 < nk) GSTAGE(cur ^ 1, (t + 1) * 64);

#pragma unroll
        for (int kb = 0; kb < 2; ++kb) {
            const int ca = ((kb * 4 + hi4) ^ sx) * 8;
            bh8 af[4], bfv[4];
#pragma unroll
            for (int i = 0; i < 4; ++i) {
                af[i]  = *reinterpret_cast<const bh8*>(&As[cur][(wr + i * 16 + fr) * 64 + ca]);
                bfv[i] = *reinterpret_cast<const bh8*>(&Bs[cur][(wc + i * 16 + fr) * 64 + ca]);
            }
#pragma unroll
            for (int i = 0; i < 4; ++i)
#pragma unroll
                for (int j = 0; j < 4; ++j)
                    acc[i][j] = __builtin_amdgcn_mfma_f32_16x16x32_bf16(af[i], bfv[j], acc[i][j], 0, 0, 0);
        }
        __syncthreads();
    }
#undef GSTAGE

    const int orow = hi4 * 4, ocol = fr;
#pragma unroll
    for (int i = 0; i < 4; ++i)
#pragma unroll
        for (int j = 0; j < 4; ++j)
#pragma unroll
            for (int e = 0; e < 4; ++e) {
                float v = acc[i][j][e];
                size_t off = (size_t)(row0 + wr + i * 16 + orow + e) * N + col0 + wc + j * 16 + ocol;
                if constexpr (__is_same(OT, u16)) C[off] = bf16u(v);
                else C[off] = v;
            }
}

// -------- bf16 NT GEMM, 128x64, BK=64, dbuf, XOR-swizzled LDS ----------------
template<typename OT>
__global__ __launch_bounds__(256) void gemm_nt64(const u16* __restrict__ A,
                                                 const u16* __restrict__ B,
                                                 OT* __restrict__ C,
                                                 int M, int N, int K) {
    __shared__ u16 As[2][128 * 64];      // 32 KiB
    __shared__ u16 Bs[2][64 * 64];       // 16 KiB  (total 48 KiB)
    const int tid = threadIdx.x;
    const int wid = tid >> 6, lane = tid & 63;

    const int gx = gridDim.x, gy = gridDim.y;
    int tx = blockIdx.x, ty = blockIdx.y;
    {
        int total = gx * gy;
        if ((total & 63) == 0 && gx >= 8) {
            int chunk = total >> 3;
            int srows = chunk >> 3;
            if (srows > 0 && (gy % srows) == 0) {
                int bid = blockIdx.y * gx + blockIdx.x;
                int xcd = bid & 7, loc = bid >> 3;
                int nsx = gx >> 3;
                int sqx = xcd % nsx, sqy = xcd / nsx;
                tx = sqx * 8 + (loc & 7);
                ty = sqy * srows + (loc >> 3);
            }
        }
    }
    const int row0 = ty * 128, col0 = tx * 64;
    const int wr = (wid >> 1) * 64, wc = (wid & 1) * 32;

    f4 acc[4][2] = {};
    const int fr = lane & 15, hi4 = lane >> 4;
    const int sx = fr & 7;

#define GSTAGE64(b, k0)                                                           \
    {                                                                             \
        _Pragma("unroll")                                                         \
        for (int i = 0; i < 4; ++i) {                                             \
            int rb = i * 32 + wid * 8;                                            \
            int row = rb + (lane >> 3);                                           \
            int ck = (lane & 7) ^ (lane >> 3);                                    \
            __builtin_amdgcn_global_load_lds(                                     \
                (const GAS void*)(A + (size_t)(row0 + row) * K + (k0) + ck * 8),  \
                (LAS void*)(As[b] + rb * 64), 16, 0, 0);                          \
        }                                                                         \
        _Pragma("unroll")                                                         \
        for (int i = 0; i < 2; ++i) {                                             \
            int rb = wid * 16 + i * 8;                                            \
            int row = rb + (lane >> 3);                                           \
            int ck = (lane & 7) ^ (lane >> 3);                                    \
            __builtin_amdgcn_global_load_lds(                                     \
                (const GAS void*)(B + (size_t)(col0 + row) * K + (k0) + ck * 8),  \
                (LAS void*)(Bs[b] + rb * 64), 16, 0, 0);                          \
        }                                                                         \
    }

    GSTAGE64(0, 0);
    __syncthreads();

    const int nk = K >> 6;
    for (int t = 0; t < nk; ++t) {
        const int cur = t & 1;
        if (t + 1 < nk) GSTAGE64(cur ^ 1, (t + 1) * 64);

#pragma unroll
        for (int kb = 0; kb < 2; ++kb) {
            const int ca = ((kb * 4 + hi4) ^ sx) * 8;
            bh8 af[4], bfv[2];
#pragma unroll
            for (int i = 0; i < 4; ++i)
                af[i] = *reinterpret_cast<const bh8*>(&As[cur][(wr + i * 16 + fr) * 64 + ca]);
#pragma unroll
            for (int j = 0; j < 2; ++j)
                bfv[j] = *reinterpret_cast<const bh8*>(&Bs[cur][(wc + j * 16 + fr) * 64 + ca]);
#pragma unroll
            for (int i = 0; i < 4; ++i)
#pragma unroll
                for (int j = 0; j < 2; ++j)
                    acc[i][j] = __builtin_amdgcn_mfma_f32_16x16x32_bf16(af[i], bfv[j], acc[i][j], 0, 0, 0);
        }
        __syncthreads();
    }
#undef GSTAGE64

    const int orow = hi4 * 4, ocol = fr;
#pragma unroll
    for (int i = 0; i < 4; ++i)
#pragma unroll
        for (int j = 0; j < 2; ++j)
#pragma unroll
            for (int e = 0; e < 4; ++e) {
                float v = acc[i][j][e];
                size_t off = (size_t)(row0 + wr + i * 16 + orow + e) * N + col0 + wc + j * 16 + ocol;
                if constexpr (__is_same(OT, u16)) C[off] = bf16u(v);
                else C[off] = v;
            }
}

// ---------------- q prep: RMS + partial RoPE + fold SCALE*log2e, bf16 --------
__global__ __launch_bounds__(256) void qprep(const u16* __restrict__ C1b,
                                             const float* __restrict__ cosb,
                                             const float* __restrict__ sinb,
                                             const float* __restrict__ qw,
                                             u16* __restrict__ Qb) {
    constexpr float KS = 0.08838834764831845f * 1.4426950408889634f;
    int wid = threadIdx.x >> 6, lane = threadIdx.x & 63;
    int id = blockIdx.x * 4 + wid;          // (h,s) index
    int h = id >> 11, s = id & 2047;
    const u16* row = C1b + (size_t)s * 4096 + h * 256;
    float v0 = b2f(row[lane]), v1 = b2f(row[lane + 64]);
    float ss = v0 * v0 + v1 * v1;
#pragma unroll
    for (int off = 32; off; off >>= 1) ss += __shfl_xor(ss, off, 64);
    float sc = rsqrtf(ss * (1.f / 128.f) + 1e-6f);
    float q0 = v0 * sc * (1.f + qw[lane]);
    float q1 = v1 * sc * (1.f + qw[lane + 64]);
    float part = __shfl_xor(q0, 32, 64);
    float rot = (lane < 32) ? -part : part;
    float c = cosb[s * 64 + lane], sn = sinb[s * 64 + lane];
    float o0 = q0 * c + rot * sn;
    u16* dst = Qb + (size_t)h * S_LEN * HD + (size_t)s * HD;
    dst[lane] = bf16u(o0 * KS);
    dst[lane + 64] = bf16u(q1 * KS);
}

// ---------------- flash attention, swapped-QK, KV-split ----------------------
__global__ __launch_bounds__(256, 2) void attn_kernel(const u16* __restrict__ Qb,
                                                      const u16* __restrict__ Kb,
                                                      const u16* __restrict__ VTb,
                                                      u16* __restrict__ O0p,
                                                      u16* __restrict__ O1p,
                                                      float* __restrict__ M0,
                                                      float* __restrict__ L0,
                                                      float* __restrict__ M1,
                                                      float* __restrict__ L1) {
    __shared__ __align__(16) char buf[65536];          // 64 KiB
    u16* Kt0 = (u16*)buf;                              // [64 kv][128 d]
    u16* Vt0 = (u16*)(buf + 16384);                    // [128 d][64 kv]
    u16* Kt1 = (u16*)(buf + 32768);
    u16* Vt1 = (u16*)(buf + 49152);

    const int tid = threadIdx.x, wid = tid >> 6, lane = tid & 63;
    const int bid = blockIdx.x;          // 0..1023
    const int half = bid & 1;
    const int rest = bid >> 1;
    const int h = rest & 15;
    const int qb = 31 - (rest >> 4);     // LPT: longest dispatched first
    const int q0w = qb * 64 + wid * 16;
    const int h4 = h >> 2;
    const u16* Qh = Qb + (size_t)h * S_LEN * HD;
    const u16* Kh = Kb + (size_t)h4 * S_LEN * HD;
    const u16* Vh = VTb + (size_t)h4 * HD * S_LEN;
    const int fr = lane & 15, hi4 = lane >> 4;
    const int sx = fr & 7;
    constexpr float THR = 11.5f;

    const int nt0 = (qb + 1) >> 1;
    const int tb = half ? nt0 : 0;
    const int te = half ? (qb + 1) : nt0;
    const int qrow = q0w + fr;           // this lane's q-row

    bh8 qf[4];
#pragma unroll
    for (int kb = 0; kb < 4; ++kb)
        qf[kb] = *reinterpret_cast<const bh8*>(&Qh[(size_t)qrow * HD + kb * 32 + hi4 * 8]);

    f4 acc[8] = {};                      // O^T: acc[dt][j] -> d=dt*16+hi4*4+j, q=qrow
    float m_r = -1e30f, l_r = 0.f;

#define STAGE(kd, vd, t0)                                                         \
    {                                                                             \
        _Pragma("unroll")                                                         \
        for (int i = 0; i < 4; ++i) {                                             \
            int row = wid * 16 + i * 4 + (lane >> 4);                             \
            int ck = (lane & 15) ^ (row & 7);                                     \
            __builtin_amdgcn_global_load_lds(                                     \
                (const GAS void*)(Kh + (size_t)((t0) + row) * HD + ck * 8),       \
                (LAS void*)((kd) + (wid * 16 + i * 4) * HD), 16, 0, 0);           \
        }                                                                         \
        _Pragma("unroll")                                                         \
        for (int i = 0; i < 4; ++i) {                                             \
            int row = wid * 32 + i * 8 + (lane >> 3);                             \
            int cv = (lane & 7) ^ (row & 7);                                      \
            __builtin_amdgcn_global_load_lds(                                     \
                (const GAS void*)(Vh + (size_t)row * S_LEN + (t0) + cv * 8),      \
                (LAS void*)((vd) + (wid * 32 + i * 8) * KVB), 16, 0, 0);          \
        }                                                                         \
    }

    auto tile_step = [&](int t0, const u16* Ktc, const u16* Vtc, bool masked) {
        f4 z[4];
#pragma unroll
        for (int nf = 0; nf < 4; ++nf) {
            f4 zz = {};
#pragma unroll
            for (int kb = 0; kb < 4; ++kb) {
                bh8 kf = *reinterpret_cast<const bh8*>(
                    &Ktc[(nf * 16 + fr) * HD + (((kb * 4 + hi4) ^ sx) * 8)]);
                zz = __builtin_amdgcn_mfma_f32_16x16x32_bf16(kf, qf[kb], zz, 0, 0, 0);
            }
            z[nf] = zz;
        }
        if (masked) {
#pragma unroll
            for (int nf = 0; nf < 4; ++nf)
#pragma unroll
                for (int j = 0; j < 4; ++j)
                    if (t0 + nf * 16 + hi4 * 4 + j > qrow) z[nf][j] = -3.0e38f;
        }
        float v = z[0][0];
#pragma unroll
        for (int nf = 0; nf < 4; ++nf)
#pragma unroll
            for (int j = 0; j < 4; ++j) v = fmaxf(v, z[nf][j]);
        v = fmaxf(v, __shfl_xor(v, 16, 64));
        v = fmaxf(v, __shfl_xor(v, 32, 64));
        if (__any(v > m_r + THR)) {
            float nm = fmaxf(m_r, v);
            float corr = exp2f(m_r - nm);
            m_r = nm;
            l_r *= corr;
#pragma unroll
            for (int dt = 0; dt < 8; ++dt)
#pragma unroll
                for (int j = 0; j < 4; ++j) acc[dt][j] *= corr;
        }
        u32 pk[4][2];
#pragma unroll
        for (int nf = 0; nf < 4; ++nf) {
            float p0 = exp2f(z[nf][0] - m_r), p1 = exp2f(z[nf][1] - m_r);
            float p2 = exp2f(z[nf][2] - m_r), p3 = exp2f(z[nf][3] - m_r);
            l_r += (p0 + p1) + (p2 + p3);
            pk[nf][0] = pack2(p0, p1);
            pk[nf][1] = pack2(p2, p3);
        }
#pragma unroll
        for (int kk = 0; kk < 2; ++kk) {
            union { u32 w[4]; bh8 v8; } u;
            u.w[0] = pk[2 * kk][0];     u.w[1] = pk[2 * kk][1];
            u.w[2] = pk[2 * kk + 1][0]; u.w[3] = pk[2 * kk + 1][1];
            bh8 pa = u.v8;
            const int cA = kk * 4 + (hi4 >> 1);
            const int off = (hi4 & 1) * 4;
#pragma unroll
            for (int dt = 0; dt < 8; ++dt) {
                int base = (dt * 16 + fr) * KVB;
                bh4 lo = *reinterpret_cast<const bh4*>(&Vtc[base + ((cA ^ sx) * 8) + off]);
                bh4 hi = *reinterpret_cast<const bh4*>(&Vtc[base + (((cA + 2) ^ sx) * 8) + off]);
                bh8 vf = __builtin_shufflevector(lo, hi, 0, 1, 2, 3, 4, 5, 6, 7);
                acc[dt] = __builtin_amdgcn_mfma_f32_16x16x32_bf16(vf, pa, acc[dt], 0, 0, 0);
            }
        }
    };

    if (tb < te) {
        STAGE(Kt0, Vt0, tb * KVB);
        __syncthreads();
        int cur = 0;
        for (int t = tb; t < te; ++t) {
            if (t + 1 < te) {
                if (cur) STAGE(Kt0, Vt0, (t + 1) * KVB)
                else     STAGE(Kt1, Vt1, (t + 1) * KVB)
            }
            tile_step(t * KVB, cur ? Kt1 : Kt0, cur ? Vt1 : Vt0, t == qb);
            __syncthreads();             // readers done + async stage drained
            cur ^= 1;
        }
    }
#undef STAGE

    float l_tot = l_r;
    l_tot += __shfl_xor(l_tot, 16, 64);
    l_tot += __shfl_xor(l_tot, 32, 64);

    u16* Op = half ? O1p : O0p;
    float* Mp = half ? M1 : M0;
    float* Lp = half ? L1 : L0;
    if (hi4 == 0) {
        Mp[h * S_LEN + qrow] = m_r;
        Lp[h * S_LEN + qrow] = l_tot;
    }

    float* ep = (float*)buf + wid * (16 * EPS_STRIDE);
#pragma unroll
    for (int dt = 0; dt < 8; ++dt)
#pragma unroll
        for (int j = 0; j < 4; ++j)
            ep[fr * EPS_STRIDE + dt * 16 + hi4 * 4 + j] = acc[dt][j];
    asm volatile("s_waitcnt lgkmcnt(0)" ::: "memory");   // per-wave private region

    const int q_l = lane >> 2;           // 0..15
    const int c0 = (lane & 3) * 32;      // d base
    const float* eprow = ep + q_l * EPS_STRIDE + c0;
    u16* dst = Op + ((size_t)h * S_LEN + (q0w + q_l)) * HD + c0;
#pragma unroll
    for (int i2 = 0; i2 < 4; ++i2) {
        f4 a = *reinterpret_cast<const f4*>(eprow + i2 * 8);
        f4 b = *reinterpret_cast<const f4*>(eprow + i2 * 8 + 4);
        uint4 w;
        w.x = pack2(a[0], a[1]); w.y = pack2(a[2], a[3]);
        w.z = pack2(b[0], b[1]); w.w = pack2(b[2], b[3]);
        *reinterpret_cast<uint4*>(dst + i2 * 8) = w;
    }
}

// ---------------- combine: merge 2 KV-halves, gate, emit bf16 AO -------------
__global__ __launch_bounds__(256) void attn_combine(const u16* __restrict__ O0p,
                                                    const u16* __restrict__ O1p,
                                                    const float* __restrict__ M0,
                                                    const float* __restrict__ L0,
                                                    const float* __restrict__ M1,
                                                    const float* __restrict__ L1,
                                                    const u16* __restrict__ C1b,
                                                    u16* __restrict__ AO) {
    constexpr float L2E = 1.4426950408889634f;
    int idx = blockIdx.x * 256 + threadIdx.x;   // 16*2048*16 total
    int d8 = idx & 15;
    int s  = (idx >> 4) & 2047;
    int h  = idx >> 15;
    int row = h * S_LEN + s;
    float m0 = M0[row], l0 = L0[row], m1 = M1[row], l1 = L1[row];
    float m = fmaxf(m0, m1);
    float a = exp2f(m0 - m), b = exp2f(m1 - m);
    float inv = 1.f / (a * l0 + b * l1);
    bh8 o0 = *reinterpret_cast<const bh8*>(O0p + (size_t)row * HD + d8 * 8);
    bh8 o1 = *reinterpret_cast<const bh8*>(O1p + (size_t)row * HD + d8 * 8);
    bh8 g  = *reinterpret_cast<const bh8*>(C1b + (size_t)s * 4096 + h * 256 + 128 + d8 * 8);
    u32 w[4];
#pragma unroll
    for (int e = 0; e < 4; ++e) {
        float v0 = (a * b2f((u16)o0[2 * e]) + b * b2f((u16)o1[2 * e])) * inv;
        float v1 = (a * b2f((u16)o0[2 * e + 1]) + b * b2f((u16)o1[2 * e + 1])) * inv;
        v0 *= 1.f / (1.f + exp2f(-b2f((u16)g[2 * e]) * L2E));
        v1 *= 1.f / (1.f + exp2f(-b2f((u16)g[2 * e + 1]) * L2E));
        w[e] = pack2(v0, v1);
    }
    uint4 ww = {w[0], w[1], w[2], w[3]};
    *reinterpret_cast<uint4*>(AO + (size_t)s * D_MODEL + h * HD + d8 * 8) = ww;
}

extern "C" void kernel_launch(void* const* d_in, const int* in_sizes, int n_in,
                              void* d_out, int out_size, void* d_ws, size_t ws_size,
                              hipStream_t stream) {
    const float* hs   = (const float*)d_in[0];
    const float* Kc   = (const float*)d_in[1];
    const float* Vc   = (const float*)d_in[2];
    const float* cosb = (const float*)d_in[3];
    const float* sinb = (const float*)d_in[4];
    const float* Wq   = (const float*)d_in[6];
    const float* Wo   = (const float*)d_in[9];
    const float* qw   = (const float*)d_in[10];
    float* out = (float*)d_out;

    char* ws = (char*)d_ws;
    u16*   x_bf  = (u16*)ws;                          // 8 MiB  (dead after gemm1)
    u16*   Wq_bf = (u16*)(ws + (8u << 20));           // 16 MiB (dead after gemm1)
    u16*   Wo_bf = (u16*)(ws + (24u << 20));          // 8 MiB  (live till gemm2)
    u16*   K_bf  = (u16*)(ws + (32u << 20));          // 2 MiB
    u16*   VT_bf = (u16*)(ws + (34u << 20));          // 2 MiB
    u16*   C1b   = (u16*)(ws + (36u << 20));          // 16 MiB bf16 (q|gate)
    u16*   Qb    = (u16*)(ws + (68u << 20));          // 8 MiB
    u16*   AO    = (u16*)(ws + (76u << 20));          // 8 MiB
    // attn partials overlay the dead x_bf/Wq_bf region:
    u16*   O0p   = (u16*)ws;                          // 8 MiB
    u16*   O1p   = (u16*)(ws + (8u << 20));           // 8 MiB
    float* M0    = (float*)(ws + (16u << 20));        // 128 KiB each
    float* L0    = M0 + NH * S_LEN;
    float* M1    = L0 + NH * S_LEN;
    float* L1    = M1 + NH * S_LEN;

    cvt_all<<<2048, 256, 0, stream>>>(hs, x_bf, 2048 * 2048,
                                      Wq, Wq_bf, 4096 * 2048,
                                      Wo, Wo_bf, 2048 * 2048,
                                      Kc, K_bf, NKVH * S_LEN * HD);
    transpose_v<<<dim3(64, 4, NKVH), 256, 0, stream>>>(Vc, VT_bf);

    gemm_nt<u16><<<dim3(32, 16), 256, 0, stream>>>(x_bf, Wq_bf, C1b, 2048, 4096, 2048);
    qprep<<<8192, 256, 0, stream>>>(C1b, cosb, sinb, qw, Qb);
    attn_kernel<<<1024, 256, 0, stream>>>(Qb, K_bf, VT_bf, O0p, O1p, M0, L0, M1, L1);
    attn_combine<<<2048, 256, 0, stream>>>(O0p, O1p, M0, L0, M1, L1, C1b, AO);
    gemm_nt64<float><<<dim3(32, 16), 256, 0, stream>>>(AO, Wo_bf, out, 2048, 2048, 2048);
}

// Round 11
// 142.724 us; speedup vs baseline: 1.3042x; 1.0279x over previous
//
#include <hip/hip_runtime.h>
#include <hip/hip_bf16.h>

#define S_LEN 2048
#define D_MODEL 2048
#define NH 16
#define NKVH 4
#define HD 128
#define KVB 64
#define EPS_STRIDE 132   // epilogue LDS row stride (f32), 4-aligned, non-pow2

typedef __attribute__((ext_vector_type(8))) short bh8;   // 8 bf16
typedef __attribute__((ext_vector_type(4))) short bh4;   // 4 bf16
typedef __attribute__((ext_vector_type(4))) float f4;
typedef unsigned short u16;
typedef unsigned int u32;

#define GAS __attribute__((address_space(1)))
#define LAS __attribute__((address_space(3)))

__device__ __forceinline__ u16 bf16u(float x) {
    __hip_bfloat16 h = __float2bfloat16(x);
    return __builtin_bit_cast(u16, h);
}
__device__ __forceinline__ float b2f(u16 u) {
    return __builtin_bit_cast(float, (u32)u << 16);
}
__device__ __forceinline__ u32 pack2(float a, float b) {
    return (u32)bf16u(a) | ((u32)bf16u(b) << 16);
}

// ---------------- fused fp32 -> bf16 conversion (4 regions, 1 launch) --------
__device__ __forceinline__ void cvt_region(const float* __restrict__ in,
                                           u16* __restrict__ out, int n,
                                           int gtid, int gthreads) {
    for (int i = gtid * 4; i < n; i += gthreads * 4) {
        float4 v = *reinterpret_cast<const float4*>(in + i);
        ushort4 o;
        o.x = bf16u(v.x); o.y = bf16u(v.y); o.z = bf16u(v.z); o.w = bf16u(v.w);
        *reinterpret_cast<ushort4*>(out + i) = o;
    }
}
__global__ __launch_bounds__(256) void cvt_all(const float* __restrict__ a, u16* __restrict__ oa, int na,
                                               const float* __restrict__ b, u16* __restrict__ ob, int nb,
                                               const float* __restrict__ c, u16* __restrict__ oc, int nc,
                                               const float* __restrict__ d, u16* __restrict__ od, int nd) {
    int gtid = blockIdx.x * 256 + threadIdx.x;
    int gthreads = gridDim.x * 256;
    cvt_region(a, oa, na, gtid, gthreads);
    cvt_region(b, ob, nb, gtid, gthreads);
    cvt_region(c, oc, nc, gtid, gthreads);
    cvt_region(d, od, nd, gtid, gthreads);
}

// ---------------- V transpose: VT[h][d][t] = V[h][t][d], bf16 ----------------
__global__ __launch_bounds__(256) void transpose_v(const float* __restrict__ V,
                                                   u16* __restrict__ VT) {
    __shared__ float tile[32][33];
    int h = blockIdx.z;
    int t0 = blockIdx.x * 32, d0 = blockIdx.y * 32;
    int tx = threadIdx.x & 31, ty = threadIdx.x >> 5;
#pragma unroll
    for (int r = 0; r < 4; ++r) {
        int t = ty + r * 8;
        tile[t][tx] = V[(size_t)h * S_LEN * HD + (size_t)(t0 + t) * HD + d0 + tx];
    }
    __syncthreads();
#pragma unroll
    for (int r = 0; r < 4; ++r) {
        int d = ty + r * 8;
        VT[(size_t)h * HD * S_LEN + (size_t)(d0 + d) * S_LEN + t0 + tx] = bf16u(tile[tx][d]);
    }
}

// -------- bf16 NT GEMM, 128x128, BK=64, dbuf, XOR-swizzled LDS ---------------
template<typename OT>
__global__ __launch_bounds__(256) void gemm_nt(const u16* __restrict__ A,
                                               const u16* __restrict__ B,
                                               OT* __restrict__ C,
                                               int M, int N, int K) {
    __shared__ u16 As[2][128 * 64];
    __shared__ u16 Bs[2][128 * 64];
    const int tid = threadIdx.x;
    const int wid = tid >> 6, lane = tid & 63;

    const int gx = gridDim.x, gy = gridDim.y;
    int tx = blockIdx.x, ty = blockIdx.y;
    {
        int total = gx * gy;
        if ((total & 63) == 0 && gx >= 8) {
            int chunk = total >> 3;
            int srows = chunk >> 3;
            if (srows > 0 && (gy % srows) == 0) {
                int bid = blockIdx.y * gx + blockIdx.x;
                int xcd = bid & 7, loc = bid >> 3;
                int nsx = gx >> 3;
                int sqx = xcd % nsx, sqy = xcd / nsx;
                tx = sqx * 8 + (loc & 7);
                ty = sqy * srows + (loc >> 3);
            }
        }
    }
    const int row0 = ty * 128, col0 = tx * 128;
    const int wr = (wid >> 1) * 64, wc = (wid & 1) * 64;

    f4 acc[4][4] = {};
    const int fr = lane & 15, hi4 = lane >> 4;
    const int sx = fr & 7;

#define GSTAGE(b, k0)                                                             \
    {                                                                             \
        _Pragma("unroll")                                                         \
        for (int i = 0; i < 4; ++i) {                                             \
            int rb = i * 32 + wid * 8;                                            \
            int row = rb + (lane >> 3);                                           \
            int ck = (lane & 7) ^ (lane >> 3);                                    \
            __builtin_amdgcn_global_load_lds(                                     \
                (const GAS void*)(A + (size_t)(row0 + row) * K + (k0) + ck * 8),  \
                (LAS void*)(As[b] + rb * 64), 16, 0, 0);                          \
            __builtin_amdgcn_global_load_lds(                                     \
                (const GAS void*)(B + (size_t)(col0 + row) * K + (k0) + ck * 8),  \
                (LAS void*)(Bs[b] + rb * 64), 16, 0, 0);                          \
        }                                                                         \
    }

    GSTAGE(0, 0);
    __syncthreads();

    const int nk = K >> 6;
    for (int t = 0; t < nk; ++t) {
        const int cur = t & 1;
        if (t + 1 < nk) GSTAGE(cur ^ 1, (t + 1) * 64);

#pragma unroll
        for (int kb = 0; kb < 2; ++kb) {
            const int ca = ((kb * 4 + hi4) ^ sx) * 8;
            bh8 af[4], bfv[4];
#pragma unroll
            for (int i = 0; i < 4; ++i) {
                af[i]  = *reinterpret_cast<const bh8*>(&As[cur][(wr + i * 16 + fr) * 64 + ca]);
                bfv[i] = *reinterpret_cast<const bh8*>(&Bs[cur][(wc + i * 16 + fr) * 64 + ca]);
            }
#pragma unroll
            for (int i = 0; i < 4; ++i)
#pragma unroll
                for (int j = 0; j < 4; ++j)
                    acc[i][j] = __builtin_amdgcn_mfma_f32_16x16x32_bf16(af[i], bfv[j], acc[i][j], 0, 0, 0);
        }
        __syncthreads();
    }
#undef GSTAGE

    const int orow = hi4 * 4, ocol = fr;
#pragma unroll
    for (int i = 0; i < 4; ++i)
#pragma unroll
        for (int j = 0; j < 4; ++j)
#pragma unroll
            for (int e = 0; e < 4; ++e) {
                float v = acc[i][j][e];
                size_t off = (size_t)(row0 + wr + i * 16 + orow + e) * N + col0 + wc + j * 16 + ocol;
                if constexpr (__is_same(OT, u16)) C[off] = bf16u(v);
                else C[off] = v;
            }
}

// -------- bf16 NT GEMM, 128x64, BK=64, dbuf, XOR-swizzled LDS ----------------
template<typename OT>
__global__ __launch_bounds__(256) void gemm_nt64(const u16* __restrict__ A,
                                                 const u16* __restrict__ B,
                                                 OT* __restrict__ C,
                                                 int M, int N, int K) {
    __shared__ u16 As[2][128 * 64];
    __shared__ u16 Bs[2][64 * 64];
    const int tid = threadIdx.x;
    const int wid = tid >> 6, lane = tid & 63;

    const int gx = gridDim.x, gy = gridDim.y;
    int tx = blockIdx.x, ty = blockIdx.y;
    {
        int total = gx * gy;
        if ((total & 63) == 0 && gx >= 8) {
            int chunk = total >> 3;
            int srows = chunk >> 3;
            if (srows > 0 && (gy % srows) == 0) {
                int bid = blockIdx.y * gx + blockIdx.x;
                int xcd = bid & 7, loc = bid >> 3;
                int nsx = gx >> 3;
                int sqx = xcd % nsx, sqy = xcd / nsx;
                tx = sqx * 8 + (loc & 7);
                ty = sqy * srows + (loc >> 3);
            }
        }
    }
    const int row0 = ty * 128, col0 = tx * 64;
    const int wr = (wid >> 1) * 64, wc = (wid & 1) * 32;

    f4 acc[4][2] = {};
    const int fr = lane & 15, hi4 = lane >> 4;
    const int sx = fr & 7;

#define GSTAGE64(b, k0)                                                           \
    {                                                                             \
        _Pragma("unroll")                                                         \
        for (int i = 0; i < 4; ++i) {                                             \
            int rb = i * 32 + wid * 8;                                            \
            int row = rb + (lane >> 3);                                           \
            int ck = (lane & 7) ^ (lane >> 3);                                    \
            __builtin_amdgcn_global_load_lds(                                     \
                (const GAS void*)(A + (size_t)(row0 + row) * K + (k0) + ck * 8),  \
                (LAS void*)(As[b] + rb * 64), 16, 0, 0);                          \
        }                                                                         \
        _Pragma("unroll")                                                         \
        for (int i = 0; i < 2; ++i) {                                             \
            int rb = wid * 16 + i * 8;                                            \
            int row = rb + (lane >> 3);                                           \
            int ck = (lane & 7) ^ (lane >> 3);                                    \
            __builtin_amdgcn_global_load_lds(                                     \
                (const GAS void*)(B + (size_t)(col0 + row) * K + (k0) + ck * 8),  \
                (LAS void*)(Bs[b] + rb * 64), 16, 0, 0);                          \
        }                                                                         \
    }

    GSTAGE64(0, 0);
    __syncthreads();

    const int nk = K >> 6;
    for (int t = 0; t < nk; ++t) {
        const int cur = t & 1;
        if (t + 1 < nk) GSTAGE64(cur ^ 1, (t + 1) * 64);

#pragma unroll
        for (int kb = 0; kb < 2; ++kb) {
            const int ca = ((kb * 4 + hi4) ^ sx) * 8;
            bh8 af[4], bfv[2];
#pragma unroll
            for (int i = 0; i < 4; ++i)
                af[i] = *reinterpret_cast<const bh8*>(&As[cur][(wr + i * 16 + fr) * 64 + ca]);
#pragma unroll
            for (int j = 0; j < 2; ++j)
                bfv[j] = *reinterpret_cast<const bh8*>(&Bs[cur][(wc + j * 16 + fr) * 64 + ca]);
#pragma unroll
            for (int i = 0; i < 4; ++i)
#pragma unroll
                for (int j = 0; j < 2; ++j)
                    acc[i][j] = __builtin_amdgcn_mfma_f32_16x16x32_bf16(af[i], bfv[j], acc[i][j], 0, 0, 0);
        }
        __syncthreads();
    }
#undef GSTAGE64

    const int orow = hi4 * 4, ocol = fr;
#pragma unroll
    for (int i = 0; i < 4; ++i)
#pragma unroll
        for (int j = 0; j < 2; ++j)
#pragma unroll
            for (int e = 0; e < 4; ++e) {
                float v = acc[i][j][e];
                size_t off = (size_t)(row0 + wr + i * 16 + orow + e) * N + col0 + wc + j * 16 + ocol;
                if constexpr (__is_same(OT, u16)) C[off] = bf16u(v);
                else C[off] = v;
            }
}

// ---------------- q prep: RMS + partial RoPE + fold SCALE*log2e, bf16 --------
__global__ __launch_bounds__(256) void qprep(const u16* __restrict__ C1b,
                                             const float* __restrict__ cosb,
                                             const float* __restrict__ sinb,
                                             const float* __restrict__ qw,
                                             u16* __restrict__ Qb) {
    constexpr float KS = 0.08838834764831845f * 1.4426950408889634f;
    int wid = threadIdx.x >> 6, lane = threadIdx.x & 63;
    int id = blockIdx.x * 4 + wid;          // (h,s) index
    int h = id >> 11, s = id & 2047;
    const u16* row = C1b + (size_t)s * 4096 + h * 256;
    float v0 = b2f(row[lane]), v1 = b2f(row[lane + 64]);
    float ss = v0 * v0 + v1 * v1;
#pragma unroll
    for (int off = 32; off; off >>= 1) ss += __shfl_xor(ss, off, 64);
    float sc = rsqrtf(ss * (1.f / 128.f) + 1e-6f);
    float q0 = v0 * sc * (1.f + qw[lane]);
    float q1 = v1 * sc * (1.f + qw[lane + 64]);
    float part = __shfl_xor(q0, 32, 64);
    float rot = (lane < 32) ? -part : part;
    float c = cosb[s * 64 + lane], sn = sinb[s * 64 + lane];
    float o0 = q0 * c + rot * sn;
    u16* dst = Qb + (size_t)h * S_LEN * HD + (size_t)s * HD;
    dst[lane] = bf16u(o0 * KS);
    dst[lane + 64] = bf16u(q1 * KS);
}

// ---------------- flash attention, swapped-QK, 32 q-rows/wave, KV-split ------
// Wave owns 32 q-rows (2 column blocks): K/V LDS frags reused across both ->
// LDS reads per FLOP halved. Blocks b and b+256 co-resident per CU carry
// complementary lengths (sum = 17 tile-steps) for exact static balance.
__global__ __launch_bounds__(256, 2) void attn_kernel(const u16* __restrict__ Qb,
                                                      const u16* __restrict__ Kb,
                                                      const u16* __restrict__ VTb,
                                                      u16* __restrict__ O0p,
                                                      u16* __restrict__ O1p,
                                                      float* __restrict__ M0,
                                                      float* __restrict__ L0,
                                                      float* __restrict__ M1,
                                                      float* __restrict__ L1) {
    __shared__ __align__(16) char buf[65536];          // 64 KiB
    u16* Kt0 = (u16*)buf;                              // [64 kv][128 d]
    u16* Vt0 = (u16*)(buf + 16384);                    // [128 d][64 kv]
    u16* Kt1 = (u16*)(buf + 32768);
    u16* Vt1 = (u16*)(buf + 49152);

    const int tid = threadIdx.x, wid = tid >> 6, lane = tid & 63;
    const int bid = blockIdx.x;          // 0..511
    int h, qb, half;
    if (bid < 256) { h = bid & 15; qb = 15 - (bid >> 4); half = 0; }
    else { int b = bid - 256; h = b & 15; qb = b >> 4; half = 1; }
    const int q0w = qb * 128 + wid * 32;               // wave's 32 q-rows
    const int h4 = h >> 2;
    const u16* Qh = Qb + (size_t)h * S_LEN * HD;
    const u16* Kh = Kb + (size_t)h4 * S_LEN * HD;
    const u16* Vh = VTb + (size_t)h4 * HD * S_LEN;
    const int fr = lane & 15, hi4 = lane >> 4;
    const int sx = fr & 7;
    constexpr float THR = 11.5f;

    const int nt0 = qb + 1;              // tiles in half0
    const int tb = half ? nt0 : 0;
    const int te = half ? (2 * qb + 2) : nt0;
    const int tmask = q0w >> 6;          // first tile needing causal mask (this wave)
    const int qrow0 = q0w + fr;
    const int qrow1 = q0w + 16 + fr;

    bh8 qf0[4], qf1[4];
#pragma unroll
    for (int kb = 0; kb < 4; ++kb) {
        qf0[kb] = *reinterpret_cast<const bh8*>(&Qh[(size_t)qrow0 * HD + kb * 32 + hi4 * 8]);
        qf1[kb] = *reinterpret_cast<const bh8*>(&Qh[(size_t)qrow1 * HD + kb * 32 + hi4 * 8]);
    }

    f4 acc0[8] = {}, acc1[8] = {};       // O^T per q-block
    float mr0 = -1e30f, lr0 = 0.f, mr1 = -1e30f, lr1 = 0.f;

#define STAGE(kd, vd, t0)                                                         \
    {                                                                             \
        _Pragma("unroll")                                                         \
        for (int i = 0; i < 4; ++i) {                                             \
            int row = wid * 16 + i * 4 + (lane >> 4);                             \
            int ck = (lane & 15) ^ (row & 7);                                     \
            __builtin_amdgcn_global_load_lds(                                     \
                (const GAS void*)(Kh + (size_t)((t0) + row) * HD + ck * 8),       \
                (LAS void*)((kd) + (wid * 16 + i * 4) * HD), 16, 0, 0);           \
        }                                                                         \
        _Pragma("unroll")                                                         \
        for (int i = 0; i < 4; ++i) {                                             \
            int row = wid * 32 + i * 8 + (lane >> 3);                             \
            int cv = (lane & 7) ^ (row & 7);                                      \
            __builtin_amdgcn_global_load_lds(                                     \
                (const GAS void*)(Vh + (size_t)row * S_LEN + (t0) + cv * 8),      \
                (LAS void*)((vd) + (wid * 32 + i * 8) * KVB), 16, 0, 0);          \
        }                                                                         \
    }

    auto tile_step = [&](int t0, const u16* Ktc, const u16* Vtc, bool masked) {
        f4 z0[4], z1[4];
#pragma unroll
        for (int nf = 0; nf < 4; ++nf) {
            f4 a = {}, b = {};
#pragma unroll
            for (int kb = 0; kb < 4; ++kb) {
                bh8 kf = *reinterpret_cast<const bh8*>(
                    &Ktc[(nf * 16 + fr) * HD + (((kb * 4 + hi4) ^ sx) * 8)]);
                a = __builtin_amdgcn_mfma_f32_16x16x32_bf16(kf, qf0[kb], a, 0, 0, 0);
                b = __builtin_amdgcn_mfma_f32_16x16x32_bf16(kf, qf1[kb], b, 0, 0, 0);
            }
            z0[nf] = a; z1[nf] = b;
        }
        if (masked) {
#pragma unroll
            for (int nf = 0; nf < 4; ++nf)
#pragma unroll
                for (int j = 0; j < 4; ++j) {
                    int kv = t0 + nf * 16 + hi4 * 4 + j;
                    if (kv > qrow0) z0[nf][j] = -3.0e38f;
                    if (kv > qrow1) z1[nf][j] = -3.0e38f;
                }
        }
        float v0 = z0[0][0], v1 = z1[0][0];
#pragma unroll
        for (int nf = 0; nf < 4; ++nf)
#pragma unroll
            for (int j = 0; j < 4; ++j) {
                v0 = fmaxf(v0, z0[nf][j]);
                v1 = fmaxf(v1, z1[nf][j]);
            }
        v0 = fmaxf(v0, __shfl_xor(v0, 16, 64));
        v0 = fmaxf(v0, __shfl_xor(v0, 32, 64));
        v1 = fmaxf(v1, __shfl_xor(v1, 16, 64));
        v1 = fmaxf(v1, __shfl_xor(v1, 32, 64));
        bool need = (v0 > mr0 + THR) || (v1 > mr1 + THR);
        if (__any(need)) {
            float nm0 = fmaxf(mr0, v0), nm1 = fmaxf(mr1, v1);
            float c0 = exp2f(mr0 - nm0), c1 = exp2f(mr1 - nm1);
            mr0 = nm0; mr1 = nm1;
            lr0 *= c0; lr1 *= c1;
#pragma unroll
            for (int dt = 0; dt < 8; ++dt)
#pragma unroll
                for (int j = 0; j < 4; ++j) {
                    acc0[dt][j] *= c0;
                    acc1[dt][j] *= c1;
                }
        }
        u32 pk0[4][2], pk1[4][2];
#pragma unroll
        for (int nf = 0; nf < 4; ++nf) {
            float a0 = exp2f(z0[nf][0] - mr0), a1 = exp2f(z0[nf][1] - mr0);
            float a2 = exp2f(z0[nf][2] - mr0), a3 = exp2f(z0[nf][3] - mr0);
            lr0 += (a0 + a1) + (a2 + a3);
            pk0[nf][0] = pack2(a0, a1);
            pk0[nf][1] = pack2(a2, a3);
            float b0 = exp2f(z1[nf][0] - mr1), b1 = exp2f(z1[nf][1] - mr1);
            float b2 = exp2f(z1[nf][2] - mr1), b3 = exp2f(z1[nf][3] - mr1);
            lr1 += (b0 + b1) + (b2 + b3);
            pk1[nf][0] = pack2(b0, b1);
            pk1[nf][1] = pack2(b2, b3);
        }
#pragma unroll
        for (int kk = 0; kk < 2; ++kk) {
            union { u32 w[4]; bh8 v8; } ua, ub;
            ua.w[0] = pk0[2 * kk][0];     ua.w[1] = pk0[2 * kk][1];
            ua.w[2] = pk0[2 * kk + 1][0]; ua.w[3] = pk0[2 * kk + 1][1];
            ub.w[0] = pk1[2 * kk][0];     ub.w[1] = pk1[2 * kk][1];
            ub.w[2] = pk1[2 * kk + 1][0]; ub.w[3] = pk1[2 * kk + 1][1];
            bh8 pa = ua.v8, pb = ub.v8;
            const int cA = kk * 4 + (hi4 >> 1);
            const int off = (hi4 & 1) * 4;
#pragma unroll
            for (int dt = 0; dt < 8; ++dt) {
                int base = (dt * 16 + fr) * KVB;
                bh4 lo = *reinterpret_cast<const bh4*>(&Vtc[base + ((cA ^ sx) * 8) + off]);
                bh4 hi = *reinterpret_cast<const bh4*>(&Vtc[base + (((cA + 2) ^ sx) * 8) + off]);
                bh8 vf = __builtin_shufflevector(lo, hi, 0, 1, 2, 3, 4, 5, 6, 7);
                acc0[dt] = __builtin_amdgcn_mfma_f32_16x16x32_bf16(vf, pa, acc0[dt], 0, 0, 0);
                acc1[dt] = __builtin_amdgcn_mfma_f32_16x16x32_bf16(vf, pb, acc1[dt], 0, 0, 0);
            }
        }
    };

    {
        STAGE(Kt0, Vt0, tb * KVB);
        __syncthreads();
        int cur = 0;
        for (int t = tb; t < te; ++t) {
            if (t + 1 < te) {
                if (cur) STAGE(Kt0, Vt0, (t + 1) * KVB)
                else     STAGE(Kt1, Vt1, (t + 1) * KVB)
            }
            tile_step(t * KVB, cur ? Kt1 : Kt0, cur ? Vt1 : Vt0, t >= tmask);
            __syncthreads();             // readers done + async stage drained
            cur ^= 1;
        }
    }
#undef STAGE

    u16* Op = half ? O1p : O0p;
    float* Mp = half ? M1 : M0;
    float* Lp = half ? L1 : L0;
    float* ep = (float*)buf + wid * (16 * EPS_STRIDE);
    const int q_l = lane >> 2;           // 0..15
    const int c0 = (lane & 3) * 32;      // d base

#define EPILOG(ACC, MR, LR, ROWOFS)                                               \
    {                                                                             \
        float lt = (LR);                                                          \
        lt += __shfl_xor(lt, 16, 64);                                             \
        lt += __shfl_xor(lt, 32, 64);                                             \
        if (hi4 == 0) {                                                           \
            Mp[h * S_LEN + q0w + (ROWOFS) + fr] = (MR);                           \
            Lp[h * S_LEN + q0w + (ROWOFS) + fr] = lt;                             \
        }                                                                         \
        _Pragma("unroll")                                                         \
        for (int dt = 0; dt < 8; ++dt)                                            \
            _Pragma("unroll")                                                     \
            for (int j = 0; j < 4; ++j)                                           \
                ep[fr * EPS_STRIDE + dt * 16 + hi4 * 4 + j] = ACC[dt][j];         \
        asm volatile("s_waitcnt lgkmcnt(0)" ::: "memory");                        \
        {                                                                         \
            const float* eprow = ep + q_l * EPS_STRIDE + c0;                      \
            u16* dst = Op + ((size_t)h * S_LEN + q0w + (ROWOFS) + q_l) * HD + c0; \
            _Pragma("unroll")                                                     \
            for (int i2 = 0; i2 < 4; ++i2) {                                      \
                f4 a = *reinterpret_cast<const f4*>(eprow + i2 * 8);              \
                f4 b = *reinterpret_cast<const f4*>(eprow + i2 * 8 + 4);          \
                uint4 w;                                                          \
                w.x = pack2(a[0], a[1]); w.y = pack2(a[2], a[3]);                 \
                w.z = pack2(b[0], b[1]); w.w = pack2(b[2], b[3]);                 \
                *reinterpret_cast<uint4*>(dst + i2 * 8) = w;                      \
            }                                                                     \
        }                                                                         \
        asm volatile("s_waitcnt lgkmcnt(0)" ::: "memory");                        \
    }

    EPILOG(acc0, mr0, lr0, 0);
    EPILOG(acc1, mr1, lr1, 16);
#undef EPILOG
}

// ---------------- combine: merge 2 KV-halves, gate, emit bf16 AO -------------
__global__ __launch_bounds__(256) void attn_combine(const u16* __restrict__ O0p,
                                                    const u16* __restrict__ O1p,
                                                    const float* __restrict__ M0,
                                                    const float* __restrict__ L0,
                                                    const float* __restrict__ M1,
                                                    const float* __restrict__ L1,
                                                    const u16* __restrict__ C1b,
                                                    u16* __restrict__ AO) {
    constexpr float L2E = 1.4426950408889634f;
    int idx = blockIdx.x * 256 + threadIdx.x;   // 16*2048*16 total
    int d8 = idx & 15;
    int s  = (idx >> 4) & 2047;
    int h  = idx >> 15;
    int row = h * S_LEN + s;
    float m0 = M0[row], l0 = L0[row], m1 = M1[row], l1 = L1[row];
    float m = fmaxf(m0, m1);
    float a = exp2f(m0 - m), b = exp2f(m1 - m);
    float inv = 1.f / (a * l0 + b * l1);
    bh8 o0 = *reinterpret_cast<const bh8*>(O0p + (size_t)row * HD + d8 * 8);
    bh8 o1 = *reinterpret_cast<const bh8*>(O1p + (size_t)row * HD + d8 * 8);
    bh8 g  = *reinterpret_cast<const bh8*>(C1b + (size_t)s * 4096 + h * 256 + 128 + d8 * 8);
    u32 w[4];
#pragma unroll
    for (int e = 0; e < 4; ++e) {
        float v0 = (a * b2f((u16)o0[2 * e]) + b * b2f((u16)o1[2 * e])) * inv;
        float v1 = (a * b2f((u16)o0[2 * e + 1]) + b * b2f((u16)o1[2 * e + 1])) * inv;
        v0 *= 1.f / (1.f + exp2f(-b2f((u16)g[2 * e]) * L2E));
        v1 *= 1.f / (1.f + exp2f(-b2f((u16)g[2 * e + 1]) * L2E));
        w[e] = pack2(v0, v1);
    }
    uint4 ww = {w[0], w[1], w[2], w[3]};
    *reinterpret_cast<uint4*>(AO + (size_t)s * D_MODEL + h * HD + d8 * 8) = ww;
}

extern "C" void kernel_launch(void* const* d_in, const int* in_sizes, int n_in,
                              void* d_out, int out_size, void* d_ws, size_t ws_size,
                              hipStream_t stream) {
    const float* hs   = (const float*)d_in[0];
    const float* Kc   = (const float*)d_in[1];
    const float* Vc   = (const float*)d_in[2];
    const float* cosb = (const float*)d_in[3];
    const float* sinb = (const float*)d_in[4];
    const float* Wq   = (const float*)d_in[6];
    const float* Wo   = (const float*)d_in[9];
    const float* qw   = (const float*)d_in[10];
    float* out = (float*)d_out;

    char* ws = (char*)d_ws;
    u16*   x_bf  = (u16*)ws;                          // 8 MiB  (dead after gemm1)
    u16*   Wq_bf = (u16*)(ws + (8u << 20));           // 16 MiB (dead after gemm1)
    u16*   Wo_bf = (u16*)(ws + (24u << 20));          // 8 MiB  (live till gemm2)
    u16*   K_bf  = (u16*)(ws + (32u << 20));          // 2 MiB
    u16*   VT_bf = (u16*)(ws + (34u << 20));          // 2 MiB
    u16*   C1b   = (u16*)(ws + (36u << 20));          // 16 MiB bf16 (q|gate)
    u16*   Qb    = (u16*)(ws + (68u << 20));          // 8 MiB
    u16*   AO    = (u16*)(ws + (76u << 20));          // 8 MiB
    // attn partials overlay the dead x_bf/Wq_bf region:
    u16*   O0p   = (u16*)ws;                          // 8 MiB
    u16*   O1p   = (u16*)(ws + (8u << 20));           // 8 MiB
    float* M0    = (float*)(ws + (16u << 20));        // 128 KiB each
    float* L0    = M0 + NH * S_LEN;
    float* M1    = L0 + NH * S_LEN;
    float* L1    = M1 + NH * S_LEN;

    cvt_all<<<2048, 256, 0, stream>>>(hs, x_bf, 2048 * 2048,
                                      Wq, Wq_bf, 4096 * 2048,
                                      Wo, Wo_bf, 2048 * 2048,
                                      Kc, K_bf, NKVH * S_LEN * HD);
    transpose_v<<<dim3(64, 4, NKVH), 256, 0, stream>>>(Vc, VT_bf);

    gemm_nt<u16><<<dim3(32, 16), 256, 0, stream>>>(x_bf, Wq_bf, C1b, 2048, 4096, 2048);
    qprep<<<8192, 256, 0, stream>>>(C1b, cosb, sinb, qw, Qb);
    attn_kernel<<<512, 256, 0, stream>>>(Qb, K_bf, VT_bf, O0p, O1p, M0, L0, M1, L1);
    attn_combine<<<2048, 256, 0, stream>>>(O0p, O1p, M0, L0, M1, L1, C1b, AO);
    gemm_nt64<float><<<dim3(32, 16), 256, 0, stream>>>(AO, Wo_bf, out, 2048, 2048, 2048);
}